// Round 12
// baseline (216.095 us; speedup 1.0000x reference)
//
#include <hip/hip_runtime.h>
#include <math.h>

// CorrectionRegressor fused kernel, round 12: fit the 64-reg/8-wave config cleanly.
// m69: waves/CU steps at VGPR 64/128/256 -> occupancy choice is binary
// (<=64 total regs: 8 waves/SIMD; <=128: 4 waves). 8-wave+spills (r11, 203us)
// beats 4-wave clean (r9/r10, 236us); target = 8-wave with NO spills.
// Change vs r11: heads ks-outer (a_hi live 4 regs not 16; bias loads deferred
// until after MFMA loop) + __launch_bounds__(512, 8) = explicit 64-reg budget.

#define THREADS 512
#define ROWS 64

typedef __attribute__((ext_vector_type(8))) short short8;
typedef __attribute__((ext_vector_type(4))) float f32x4;
typedef __attribute__((ext_vector_type(2))) float f32x2;
typedef __attribute__((ext_vector_type(4))) unsigned int u32x4;

// d_ws layout in short8 (16 B) units:
#define W2F_OFF   0        // [h2][ks8][nt8][lane64]  = 8192 frags
#define W1F_OFF   8192     // [h2][nt16][lane64]      = 2048 frags
#define WSHF_OFF  10240    // [ks4][nt4][lane64]      = 1024 frags (hi only)
#define WISOF_OFF 11264    // [iso12][ks4][nt4][lane64]= 12288 frags (hi only)
#define F32_OFF   23552    // float region: contrib[12][64], gate[12]

__device__ __forceinline__ unsigned short f2bf(float f) {   // RNE f32->bf16
  unsigned int u = __float_as_uint(f);
  return (unsigned short)((u + 0x7FFFu + ((u >> 16) & 1u)) >> 16);
}
__device__ __forceinline__ float bf2f(unsigned short b) {
  return __uint_as_float(((unsigned int)b) << 16);
}
__device__ __forceinline__ f32x2 splat2(float s) { f32x2 r = {s, s}; return r; }
__device__ __forceinline__ f32x2 abs2(f32x2 v) {
  f32x2 r; r.x = __builtin_fabsf(v.x); r.y = __builtin_fabsf(v.y); return r;
}
__device__ __forceinline__ unsigned int cvtpk_bf16(f32x2 v) {
  unsigned int r;
  asm("v_cvt_pk_bf16_f32 %0, %1, %2" : "=v"(r) : "v"(v.x), "v"(v.y));
  return r;
}
__device__ __forceinline__ void split2(f32x2 v, unsigned int& hi2, unsigned int& lo2) {
  hi2 = cvtpk_bf16(v);
  f32x2 hf;
  hf.x = __uint_as_float(hi2 << 16);
  hf.y = __uint_as_float(hi2 & 0xFFFF0000u);
  f32x2 rem = v - hf;
  lo2 = cvtpk_bf16(rem);
}
// pair GELU, exact-erf via A&S 7.1.26 (|eps|<=1.5e-7), branch-free.
__device__ __forceinline__ f32x2 gelu2(f32x2 v) {
  f32x2 x  = v * 0.70710678118654752f;
  f32x2 ax = abs2(x);
  f32x2 den = ax * 0.3275911f + 1.0f;
  f32x2 t; t.x = __builtin_amdgcn_rcpf(den.x); t.y = __builtin_amdgcn_rcpf(den.y);
  f32x2 nx2 = -x * x;
  f32x2 e; e.x = __expf(nx2.x); e.y = __expf(nx2.y);
  f32x2 p = t * 1.061405429f + splat2(-1.453152027f);
  p = t * p + 1.421413741f;
  p = t * p + splat2(-0.284496736f);
  p = t * p + 0.254829592f;
  p = p * t;
  f32x2 r = splat2(1.0f) - p * e;
  r.x = __builtin_copysignf(r.x, x.x);
  r.y = __builtin_copysignf(r.y, x.y);
  f32x2 s = r * 0.5f + 0.5f;
  return v * s;
}

// ---- prep: weight fragments + per-iso tables into d_ws (unchanged) -------
__global__ void prep_frags(const float* __restrict__ W1, const float* __restrict__ W2,
                           const float* __restrict__ Wsh1, const float* __restrict__ bsh1,
                           const float* __restrict__ Wiso1,
                           const float* __restrict__ iso_embed,
                           const float* __restrict__ Wg, const float* __restrict__ bg,
                           unsigned short* __restrict__ wsf) {
  int id = blockIdx.x * 256 + threadIdx.x;
  float* wsc = (float*)(wsf + (size_t)F32_OFF * 8);
  if (id < 8192) {                      // W2 frags hi/lo
    int l = id & 63, nt = (id >> 6) & 7, ks = (id >> 9) & 7, h = id >> 12;
    int n = nt * 16 + (l & 15);
    int k0 = ks * 32 + (l >> 4) * 8;
    short8 pk;
    #pragma unroll
    for (int j = 0; j < 8; j++) {
      float v = W2[(k0 + j) * 128 + n];
      unsigned short hb = f2bf(v);
      pk[j] = (short)(h ? f2bf(v - bf2f(hb)) : hb);
    }
    *(short8*)(wsf + (size_t)id * 8) = pk;
  } else if (id < 10240) {              // W1 frags hi/lo
    int id2 = id - 8192;
    int l = id2 & 63, nt = (id2 >> 6) & 15, h = id2 >> 10;
    int n = nt * 16 + (l & 15);
    int k0 = (l >> 4) * 8;
    short8 pk;
    #pragma unroll
    for (int j = 0; j < 8; j++) {
      float v = W1[(k0 + j) * 256 + n];
      unsigned short hb = f2bf(v);
      pk[j] = (short)(h ? f2bf(v - bf2f(hb)) : hb);
    }
    *(short8*)(wsf + (size_t)id * 8) = pk;
  } else if (id < 11264) {              // Wsh1[:128] frags, hi only
    int fid = id - 10240;
    int l = fid & 63, nt = (fid >> 6) & 3, ks = fid >> 8;
    int n = nt * 16 + (l & 15);
    int k0 = ks * 32 + (l >> 4) * 8;
    short8 pk;
    #pragma unroll
    for (int j = 0; j < 8; j++) pk[j] = (short)f2bf(Wsh1[(k0 + j) * 64 + n]);
    *(short8*)(wsf + (size_t)id * 8) = pk;
  } else if (id < 23552) {              // Wiso1 frags, hi only
    int fid = id - 11264;
    int l = fid & 63, nt = (fid >> 6) & 3, ks = (fid >> 8) & 3, iso = fid >> 10;
    int n = nt * 16 + (l & 15);
    int k0 = ks * 32 + (l >> 4) * 8;
    short8 pk;
    #pragma unroll
    for (int j = 0; j < 8; j++) pk[j] = (short)f2bf(Wiso1[iso * 8192 + (k0 + j) * 64 + n]);
    *(short8*)(wsf + (size_t)id * 8) = pk;
  } else if (id < 24320) {              // contrib[i][n] = bsh1[n] + ie_i @ Wsh1[128:]
    int cid = id - 23552;
    int i = cid >> 6, n = cid & 63;
    float s = bsh1[n];
    #pragma unroll
    for (int e = 0; e < 8; e++) s += iso_embed[i * 8 + e] * Wsh1[(128 + e) * 64 + n];
    wsc[cid] = s;
  } else if (id < 24332) {              // gate[i]
    int i = id - 24320;
    float s = bg[0];
    #pragma unroll
    for (int e = 0; e < 8; e++) s += iso_embed[i * 8 + e] * Wg[e];
    wsc[768 + i] = 1.0f / (1.0f + expf(-s));
  }
}

#define HSTR 264   // h1-hi row stride (u16): 528 B, 16B-aligned rows
#define SSTR 136   // shared-plane row stride (u16): 272 B, 16B-aligned rows

__global__ __launch_bounds__(THREADS, 8)   // explicit 64-reg total budget: 8 waves/SIMD
void corr_reg_fused(
    const float* __restrict__ x,
    const int*   __restrict__ mol_idx,
    const int*   __restrict__ iso_idx,
    const float* __restrict__ mol_embed,
    const float* __restrict__ iso_embed,
    const float* __restrict__ b1,
    const float* __restrict__ g1,  const float* __restrict__ be1,
    const float* __restrict__ b2,
    const float* __restrict__ g2,  const float* __restrict__ be2,
    const float* __restrict__ bsh2,
    const float* __restrict__ Wsh2,
    const float* __restrict__ biso1,
    const float* __restrict__ Wiso2, const float* __restrict__ biso2,
    const unsigned short* __restrict__ wsf,
    float* __restrict__ out)
{
  // LDS total ~= 39.7 KB -> 4 blocks/CU by LDS
  __shared__ __align__(16) unsigned short pool[16896];  // 33,792 B:
      // phase A: h1-hi [64][HSTR]
      // phase B (after B4): sh_hi [64][SSTR] (17,408 B, aliases pool)
  __shared__ float ps[8][ROWS], pq[8][ROWS];            // 4096 (transposed)
  __shared__ float mu_s[ROWS], rs_s[ROWS];              // 512
  __shared__ float sp[ROWS], eo[ROWS];                  // 512
  __shared__ int   iso_s[ROWS];                         // 256
  __shared__ unsigned char slots[320];                  // 320
  __shared__ short          tile_iso[24];               // 48
  __shared__ unsigned short tile_sb[24];                // 48
  __shared__ int rcount[12], rcount2[12], roffpad[12];  // 144
  __shared__ int ntiles, nslots;                        // 8

  unsigned short (*hp)[HSTR] = (unsigned short (*)[HSTR])pool;  // h1 hi
  unsigned short* sh_hi = pool;                 // [64][SSTR] (valid after B4)

  const int t  = threadIdx.x;
  const int r0 = blockIdx.x * ROWS;
  const int l  = t & 63, w = t >> 6;         // lane, wave (8 waves)
  const int lr = l & 15, lg = l >> 4;

  const short8* wsf8 = (const short8*)wsf;
  const float*  wsc  = (const float*)(wsf + (size_t)F32_OFF * 8);
  const float*  contrib = wsc;          // [12][64]
  const float*  gtab    = wsc + 768;    // [12]

  if (t < 12) { rcount[t] = 0; rcount2[t] = 0; }
  if (t == 0) { ntiles = 4; nslots = 64; }
  if (t < 64) slots[t] = (unsigned char)t;      // shared-head tiles: identity rows
  else if (t < 320) slots[t] = 0xFF;            // pad default
  if (t < 4)  { tile_iso[t] = -1; tile_sb[t] = (unsigned short)(16 * t); }
  __syncthreads();                                    // B0

  // ---------------- phase 0: iso ids + counts -----------------------------
  if (t < ROWS) {
    int ii = iso_idx[r0 + t];
    iso_s[t] = ii;
    atomicAdd(&rcount[ii], 1);
  }
  __syncthreads();                                    // B1

  // expert-tile metadata (needs rcount); slot fill happens after B2a
  if (t < 12) {
    int c = rcount[t];
    int nsub = (c + 15) >> 4;
    if (nsub > 0) {
      int tb = atomicAdd(&ntiles, nsub);
      int sb = atomicAdd(&nslots, nsub << 4);
      roffpad[t] = sb;
      for (int s2 = 0; s2 < nsub; s2++) {
        tile_iso[tb + s2] = (short)t;
        tile_sb[tb + s2]  = (unsigned short)(sb + (s2 << 4));
      }
    }
  }

  // ---------------- layer 1 (MFMA): y1 = z @ W1 + b1, two 32-row chunks ---
  // A-frags straight from global: k-map lg0->x[0:8], lg1->x[8:16], lg2->mol_e, lg3->iso_e
  {
    const short8* w1p = wsf8 + W1F_OFF;
    short8 bh[2], bl[2];
    #pragma unroll
    for (int q = 0; q < 2; q++) {
      int nt = w * 2 + q;
      bh[q] = w1p[nt * 64 + l];
      bl[q] = w1p[(16 + nt) * 64 + l];
    }
    const int c0 = (w * 2) * 16 + lr;
    f32x2 g1p  = {g1[c0],  g1[c0 + 16]};
    f32x2 be1p = {be1[c0], be1[c0 + 16]};
    float bn0 = b1[c0], bn1 = b1[c0 + 16];

    for (int half = 0; half < 2; half++) {
      f32x4 acc[2][2];                      // only 16 regs live per chunk
      short8 zah[2], zal[2];
      #pragma unroll
      for (int mt = 0; mt < 2; mt++) {
        int row = r0 + (half * 2 + mt) * 16 + lr;
        const float* src;
        if (lg == 0)      src = x + (size_t)row * 16;
        else if (lg == 1) src = x + (size_t)row * 16 + 8;
        else if (lg == 2) src = mol_embed + mol_idx[row] * 8;
        else              src = iso_embed + iso_idx[row] * 8;
        float4 v0 = *(const float4*)src;
        float4 v1 = *(const float4*)(src + 4);
        float vv[8] = {v0.x, v0.y, v0.z, v0.w, v1.x, v1.y, v1.z, v1.w};
        u32x4 hv, lv;
        #pragma unroll
        for (int j2 = 0; j2 < 4; j2++) {
          f32x2 p = {vv[2 * j2], vv[2 * j2 + 1]};
          unsigned int h2, l2; split2(p, h2, l2);
          hv[j2] = h2; lv[j2] = l2;
        }
        zah[mt] = __builtin_bit_cast(short8, hv);
        zal[mt] = __builtin_bit_cast(short8, lv);
      }
      #pragma unroll
      for (int mt = 0; mt < 2; mt++)
        #pragma unroll
        for (int q = 0; q < 2; q++) {
          f32x4 a_ = {0.f, 0.f, 0.f, 0.f};
          a_ = __builtin_amdgcn_mfma_f32_16x16x32_bf16(zah[mt], bh[q], a_, 0, 0, 0);
          a_ = __builtin_amdgcn_mfma_f32_16x16x32_bf16(zah[mt], bl[q], a_, 0, 0, 0);
          a_ = __builtin_amdgcn_mfma_f32_16x16x32_bf16(zal[mt], bh[q], a_, 0, 0, 0);
          acc[mt][q] = a_;
        }
      #pragma unroll
      for (int mt = 0; mt < 2; mt++)
        #pragma unroll
        for (int i = 0; i < 4; i++) {
          acc[mt][0][i] += bn0; acc[mt][1][i] += bn1;
        }
      #pragma unroll
      for (int mt = 0; mt < 2; mt++)
        #pragma unroll
        for (int i = 0; i < 4; i++) {
          float sm = acc[mt][0][i] + acc[mt][1][i];
          float sq = acc[mt][0][i]*acc[mt][0][i] + acc[mt][1][i]*acc[mt][1][i];
          #pragma unroll
          for (int m = 1; m < 16; m <<= 1) { sm += __shfl_xor(sm, m); sq += __shfl_xor(sq, m); }
          if (lr == 0) { int row = (half * 2 + mt) * 16 + lg * 4 + i; ps[w][row] = sm; pq[w][row] = sq; }
        }
      __syncthreads();                                // B2a / B2c

      if (half == 0 && t < ROWS) {                    // slot fill, once
        int ii = iso_s[t];
        int pos = atomicAdd(&rcount2[ii], 1);
        slots[roffpad[ii] + pos] = (unsigned char)t;
      }
      if (t < 32) {                                   // stats for this chunk's rows
        int row = half * 32 + t;
        float su = 0.f, sq = 0.f;
        #pragma unroll
        for (int j = 0; j < 8; j++) { su += ps[j][row]; sq += pq[j][row]; }
        float mu = su * (1.0f / 256.0f);
        float var = sq * (1.0f / 256.0f) - mu * mu;
        mu_s[row] = mu; rs_s[row] = rsqrtf(var + 1e-5f);
      }
      __syncthreads();                                // B2b / B2d

      // LN1 + GELU -> h1 hi-only bf16, this chunk's rows (acc dies here)
      #pragma unroll
      for (int mt = 0; mt < 2; mt++)
        #pragma unroll
        for (int i = 0; i < 4; i++) {
          int row = (half * 2 + mt) * 16 + lg * 4 + i;
          float mu = mu_s[row], rs = rs_s[row];
          f32x2 y = {acc[mt][0][i], acc[mt][1][i]};
          f32x2 t1 = g1p * rs;
          f32x2 t2 = splat2(-mu) * t1 + be1p;
          f32x2 gg = gelu2(y * t1 + t2);
          unsigned int h2 = cvtpk_bf16(gg);
          hp[row][c0]      = (unsigned short)h2;
          hp[row][c0 + 16] = (unsigned short)(h2 >> 16);
        }
    }
  }
  __syncthreads();                                    // B3

  // ---------------- layer 2 (MFMA): y2 = h1_hi @ (W2h + W2l) + b2 ---------
  f32x4 a2[4];
  {
    const short8* w2p = wsf8 + W2F_OFF;
    #pragma unroll
    for (int mt = 0; mt < 4; mt++) { f32x4 zf = {0.f,0.f,0.f,0.f}; a2[mt] = zf; }
    for (int ks = 0; ks < 8; ks++) {
      int k0 = ks * 32 + lg * 8;
      short8 bh = w2p[(ks * 8 + w) * 64 + l];
      short8 bl = w2p[((8 + ks) * 8 + w) * 64 + l];
      #pragma unroll
      for (int mt = 0; mt < 4; mt++) {
        short8 ah = *(const short8*)&hp[mt * 16 + lr][k0];
        a2[mt] = __builtin_amdgcn_mfma_f32_16x16x32_bf16(ah, bh, a2[mt], 0, 0, 0);
        a2[mt] = __builtin_amdgcn_mfma_f32_16x16x32_bf16(ah, bl, a2[mt], 0, 0, 0);
      }
    }
    float bn = b2[w * 16 + lr];
    f32x4 bv = {bn, bn, bn, bn};
    #pragma unroll
    for (int mt = 0; mt < 4; mt++) a2[mt] = a2[mt] + bv;
    #pragma unroll
    for (int mt = 0; mt < 4; mt++)
      #pragma unroll
      for (int i = 0; i < 4; i++) {
        float sm = a2[mt][i];
        float sq = a2[mt][i] * a2[mt][i];
        #pragma unroll
        for (int m = 1; m < 16; m <<= 1) { sm += __shfl_xor(sm, m); sq += __shfl_xor(sq, m); }
        if (lr == 0) { int row = mt * 16 + lg * 4 + i; ps[w][row] = sm; pq[w][row] = sq; }
      }
  }
  __syncthreads();                                    // B4 (all hp reads done)

  // ---------------- LN2 stats pass ----------------------------------------
  if (t < ROWS) {
    float su = 0.f, sq = 0.f;
    #pragma unroll
    for (int j = 0; j < 8; j++) { su += ps[j][t]; sq += pq[j][t]; }
    float mu = su * (1.0f / 128.0f);
    float var = sq * (1.0f / 128.0f) - mu * mu;
    mu_s[t] = mu; rs_s[t] = rsqrtf(var + 1e-5f);
  }
  __syncthreads();                                    // B4b

  // ---------------- LN2 + GELU -> shared bf16 hi plane (alias) ------------
  {
    int c0 = w * 16 + lr;
    float g2c = g2[c0], be2c = be2[c0];
    #pragma unroll
    for (int mt = 0; mt < 4; mt++)
      #pragma unroll
      for (int i2 = 0; i2 < 4; i2 += 2) {
        int row0 = mt * 16 + lg * 4 + i2;
        int row1 = row0 + 1;
        f32x2 t1 = {g2c * rs_s[row0], g2c * rs_s[row1]};
        f32x2 t2 = {be2c - mu_s[row0] * t1.x, be2c - mu_s[row1] * t1.y};
        f32x2 y = {a2[mt][i2], a2[mt][i2 + 1]};
        f32x2 gg = gelu2(y * t1 + t2);
        unsigned int h2 = cvtpk_bf16(gg);
        sh_hi[row0 * SSTR + c0] = (unsigned short)h2;
        sh_hi[row1 * SSTR + c0] = (unsigned short)(h2 >> 16);
      }
  }
  __syncthreads();                                    // B5

  // ---------------- heads: ks-outer MFMA tile loop (low pressure) ---------
  {
    float bsh2v = bsh2[0];
    int ntl = ntiles;
    for (int tt = w; tt < ntl; tt += 8) {
      int iso = tile_iso[tt];             // -1 => shared head tile
      int sb  = tile_sb[tt];
      int ar  = slots[sb + lr] & 63;      // pad (0xFF) -> row 63 reads, write-masked
      const short8* bp = (iso < 0) ? (wsf8 + WSHF_OFF) : (wsf8 + WISOF_OFF + iso * 1024);
      f32x4 c[4];
      #pragma unroll
      for (int nt = 0; nt < 4; nt++) { f32x4 zf = {0.f,0.f,0.f,0.f}; c[nt] = zf; }
      #pragma unroll
      for (int ks = 0; ks < 4; ks++) {
        short8 a_hi = *(const short8*)&sh_hi[ar * SSTR + ks * 32 + lg * 8];
        #pragma unroll
        for (int nt = 0; nt < 4; nt++) {
          short8 b = bp[(ks * 4 + nt) * 64 + l];
          c[nt] = __builtin_amdgcn_mfma_f32_16x16x32_bf16(a_hi, b, c[nt], 0, 0, 0);
        }
      }
      int rws[4];
      #pragma unroll
      for (int i = 0; i < 4; i++) rws[i] = slots[sb + lg * 4 + i];
      float accv[4];
      if (iso < 0) {
        f32x2 w01 = {Wsh2[lr], Wsh2[16 + lr]};
        f32x2 w23 = {Wsh2[32 + lr], Wsh2[48 + lr]};
        #pragma unroll
        for (int i = 0; i < 4; i++) {
          const float* cb = contrib + iso_s[rws[i]] * 64;
          f32x2 v01 = (f32x2){c[0][i], c[1][i]} + (f32x2){cb[lr], cb[16 + lr]};
          f32x2 v23 = (f32x2){c[2][i], c[3][i]} + (f32x2){cb[32 + lr], cb[48 + lr]};
          f32x2 g01 = gelu2(v01), g23 = gelu2(v23);
          float a = g01.x * w01.x;
          a = __builtin_fmaf(g01.y, w01.y, a);
          a = __builtin_fmaf(g23.x, w23.x, a);
          a = __builtin_fmaf(g23.y, w23.y, a);
          accv[i] = a;
        }
      } else {
        f32x2 b01 = {biso1[iso * 64 + lr],      biso1[iso * 64 + 16 + lr]};
        f32x2 b23 = {biso1[iso * 64 + 32 + lr], biso1[iso * 64 + 48 + lr]};
        f32x2 x01 = {Wiso2[iso * 64 + lr],      Wiso2[iso * 64 + 16 + lr]};
        f32x2 x23 = {Wiso2[iso * 64 + 32 + lr], Wiso2[iso * 64 + 48 + lr]};
        #pragma unroll
        for (int i = 0; i < 4; i++) {
          f32x2 g01 = gelu2((f32x2){c[0][i], c[1][i]} + b01);
          f32x2 g23 = gelu2((f32x2){c[2][i], c[3][i]} + b23);
          float a = g01.x * x01.x;
          a = __builtin_fmaf(g01.y, x01.y, a);
          a = __builtin_fmaf(g23.x, x23.x, a);
          a = __builtin_fmaf(g23.y, x23.y, a);
          accv[i] = a;
        }
      }
      float tail = (iso < 0) ? bsh2v : biso2[iso];
      #pragma unroll
      for (int i = 0; i < 4; i++) {
        float a = accv[i];
        a += __shfl_xor(a, 1); a += __shfl_xor(a, 2);
        a += __shfl_xor(a, 4); a += __shfl_xor(a, 8);
        if (lr == 0) {
          int r = rws[i];
          if (iso < 0) sp[r] = a + tail;
          else if (r != 0xFF) eo[r] = a + tail;
        }
      }
    }
  }
  __syncthreads();                                    // B6

  // ---------------- epilogue: gated combine -------------------------------
  if (t < ROWS) {
    int r = t;
    float gate = gtab[iso_s[r]];
    out[r0 + r] = gate * eo[r] + (1.0f - gate) * sp[r];
  }
}

extern "C" void kernel_launch(void* const* d_in, const int* in_sizes, int n_in,
                              void* d_out, int out_size, void* d_ws, size_t ws_size,
                              hipStream_t stream) {
  const float* x         = (const float*)d_in[0];
  const int*   mol_idx   = (const int*)  d_in[1];
  const int*   iso_idx   = (const int*)  d_in[2];
  const float* mol_embed = (const float*)d_in[3];
  const float* iso_embed = (const float*)d_in[4];
  const float* W1  = (const float*)d_in[5];
  const float* b1  = (const float*)d_in[6];
  const float* g1  = (const float*)d_in[7];
  const float* be1 = (const float*)d_in[8];
  const float* W2  = (const float*)d_in[9];
  const float* b2  = (const float*)d_in[10];
  const float* g2  = (const float*)d_in[11];
  const float* be2 = (const float*)d_in[12];
  const float* Wsh1 = (const float*)d_in[13];
  const float* bsh1 = (const float*)d_in[14];
  const float* Wsh2 = (const float*)d_in[15];
  const float* bsh2 = (const float*)d_in[16];
  const float* Wiso1 = (const float*)d_in[17];
  const float* biso1 = (const float*)d_in[18];
  const float* Wiso2 = (const float*)d_in[19];
  const float* biso2 = (const float*)d_in[20];
  const float* Wg = (const float*)d_in[21];
  const float* bg = (const float*)d_in[22];
  float* out = (float*)d_out;
  unsigned short* wsf = (unsigned short*)d_ws;   // needs ~380 KB

  const int B = in_sizes[0] / 16;       // 262144
  const int grid = B / ROWS;            // 4096 blocks

  hipLaunchKernelGGL(prep_frags, dim3(96), dim3(256), 0, stream,
                     W1, W2, Wsh1, bsh1, Wiso1, iso_embed, Wg, bg, wsf);
  hipLaunchKernelGGL(corr_reg_fused, dim3(grid), dim3(THREADS), 0, stream,
                     x, mol_idx, iso_idx, mol_embed, iso_embed,
                     b1, g1, be1, b2, g2, be2,
                     bsh2, Wsh2, biso1, Wiso2, biso2, wsf, out);
}

// Round 14
// 200.292 us; speedup vs baseline: 1.0789x; 1.0789x over previous
//
#include <hip/hip_runtime.h>
#include <math.h>

// CorrectionRegressor fused kernel, round 14: r11 (best, 203us) + safe deltas.
// r13's 32x32x16 layer-2 FAILED correctness: A/B fragment k-map for 32x32 is
// not verified symmetric (only C/D is HW-verified) -> reverted to 16x16x32
// everywhere (verified r3-r12). Deltas vs r11, both individually validated:
//  - heads ks-outer (r12 form, correctness-proven): A-frag live 16->4 regs
//  - 3-term A&S 7.1.25 erf (|eps|<=2.5e-5): -2 fma/elem, ~41 gelu-pairs/wave

#define THREADS 512
#define ROWS 64

typedef __attribute__((ext_vector_type(8))) short short8;
typedef __attribute__((ext_vector_type(4))) float f32x4;
typedef __attribute__((ext_vector_type(2))) float f32x2;
typedef __attribute__((ext_vector_type(4))) unsigned int u32x4;

// d_ws layout in short8 (16 B) units:
#define W2F_OFF   0        // [h2][ks8][nt8][lane64]  = 8192 frags
#define W1F_OFF   8192     // [h2][nt16][lane64]      = 2048 frags
#define WSHF_OFF  10240    // [ks4][nt4][lane64]      = 1024 frags (hi only)
#define WISOF_OFF 11264    // [iso12][ks4][nt4][lane64]= 12288 frags (hi only)
#define F32_OFF   23552    // float region: contrib[12][64], gate[12]

__device__ __forceinline__ unsigned short f2bf(float f) {   // RNE f32->bf16
  unsigned int u = __float_as_uint(f);
  return (unsigned short)((u + 0x7FFFu + ((u >> 16) & 1u)) >> 16);
}
__device__ __forceinline__ float bf2f(unsigned short b) {
  return __uint_as_float(((unsigned int)b) << 16);
}
__device__ __forceinline__ f32x2 splat2(float s) { f32x2 r = {s, s}; return r; }
__device__ __forceinline__ f32x2 abs2(f32x2 v) {
  f32x2 r; r.x = __builtin_fabsf(v.x); r.y = __builtin_fabsf(v.y); return r;
}
__device__ __forceinline__ unsigned int cvtpk_bf16(f32x2 v) {
  unsigned int r;
  asm("v_cvt_pk_bf16_f32 %0, %1, %2" : "=v"(r) : "v"(v.x), "v"(v.y));
  return r;
}
__device__ __forceinline__ void split2(f32x2 v, unsigned int& hi2, unsigned int& lo2) {
  hi2 = cvtpk_bf16(v);
  f32x2 hf;
  hf.x = __uint_as_float(hi2 << 16);
  hf.y = __uint_as_float(hi2 & 0xFFFF0000u);
  f32x2 rem = v - hf;
  lo2 = cvtpk_bf16(rem);
}
// pair GELU, erf via A&S 7.1.25 3-term (|eps|<=2.5e-5), branch-free.
__device__ __forceinline__ f32x2 gelu2(f32x2 v) {
  f32x2 x  = v * 0.70710678118654752f;
  f32x2 ax = abs2(x);
  f32x2 den = ax * 0.47047f + 1.0f;
  f32x2 t; t.x = __builtin_amdgcn_rcpf(den.x); t.y = __builtin_amdgcn_rcpf(den.y);
  f32x2 nx2 = -x * x;
  f32x2 e; e.x = __expf(nx2.x); e.y = __expf(nx2.y);
  f32x2 p = t * 0.7478556f + splat2(-0.0958798f);
  p = t * p + 0.3480242f;
  p = p * t;
  f32x2 r = splat2(1.0f) - p * e;
  r.x = __builtin_copysignf(r.x, x.x);
  r.y = __builtin_copysignf(r.y, x.y);
  f32x2 s = r * 0.5f + 0.5f;
  return v * s;
}

// ---- prep: weight fragments + per-iso tables into d_ws (r11 layout) ------
__global__ void prep_frags(const float* __restrict__ W1, const float* __restrict__ W2,
                           const float* __restrict__ Wsh1, const float* __restrict__ bsh1,
                           const float* __restrict__ Wiso1,
                           const float* __restrict__ iso_embed,
                           const float* __restrict__ Wg, const float* __restrict__ bg,
                           unsigned short* __restrict__ wsf) {
  int id = blockIdx.x * 256 + threadIdx.x;
  float* wsc = (float*)(wsf + (size_t)F32_OFF * 8);
  if (id < 8192) {                      // W2 frags hi/lo (16x16 map)
    int l = id & 63, nt = (id >> 6) & 7, ks = (id >> 9) & 7, h = id >> 12;
    int n = nt * 16 + (l & 15);
    int k0 = ks * 32 + (l >> 4) * 8;
    short8 pk;
    #pragma unroll
    for (int j = 0; j < 8; j++) {
      float v = W2[(k0 + j) * 128 + n];
      unsigned short hb = f2bf(v);
      pk[j] = (short)(h ? f2bf(v - bf2f(hb)) : hb);
    }
    *(short8*)(wsf + (size_t)id * 8) = pk;
  } else if (id < 10240) {              // W1 frags hi/lo
    int id2 = id - 8192;
    int l = id2 & 63, nt = (id2 >> 6) & 15, h = id2 >> 10;
    int n = nt * 16 + (l & 15);
    int k0 = (l >> 4) * 8;
    short8 pk;
    #pragma unroll
    for (int j = 0; j < 8; j++) {
      float v = W1[(k0 + j) * 256 + n];
      unsigned short hb = f2bf(v);
      pk[j] = (short)(h ? f2bf(v - bf2f(hb)) : hb);
    }
    *(short8*)(wsf + (size_t)id * 8) = pk;
  } else if (id < 11264) {              // Wsh1[:128] frags, hi only
    int fid = id - 10240;
    int l = fid & 63, nt = (fid >> 6) & 3, ks = fid >> 8;
    int n = nt * 16 + (l & 15);
    int k0 = ks * 32 + (l >> 4) * 8;
    short8 pk;
    #pragma unroll
    for (int j = 0; j < 8; j++) pk[j] = (short)f2bf(Wsh1[(k0 + j) * 64 + n]);
    *(short8*)(wsf + (size_t)id * 8) = pk;
  } else if (id < 23552) {              // Wiso1 frags, hi only
    int fid = id - 11264;
    int l = fid & 63, nt = (fid >> 6) & 3, ks = (fid >> 8) & 3, iso = fid >> 10;
    int n = nt * 16 + (l & 15);
    int k0 = ks * 32 + (l >> 4) * 8;
    short8 pk;
    #pragma unroll
    for (int j = 0; j < 8; j++) pk[j] = (short)f2bf(Wiso1[iso * 8192 + (k0 + j) * 64 + n]);
    *(short8*)(wsf + (size_t)id * 8) = pk;
  } else if (id < 24320) {              // contrib[i][n] = bsh1[n] + ie_i @ Wsh1[128:]
    int cid = id - 23552;
    int i = cid >> 6, n = cid & 63;
    float s = bsh1[n];
    #pragma unroll
    for (int e = 0; e < 8; e++) s += iso_embed[i * 8 + e] * Wsh1[(128 + e) * 64 + n];
    wsc[cid] = s;
  } else if (id < 24332) {              // gate[i]
    int i = id - 24320;
    float s = bg[0];
    #pragma unroll
    for (int e = 0; e < 8; e++) s += iso_embed[i * 8 + e] * Wg[e];
    wsc[768 + i] = 1.0f / (1.0f + expf(-s));
  }
}

#define HSTR 264   // h1-hi row stride (u16): 528 B, 16B-aligned rows
#define SSTR 136   // shared-plane row stride (u16): 272 B, 16B-aligned rows

__global__ __launch_bounds__(THREADS, 6)   // r11's best occupancy/spill balance
void corr_reg_fused(
    const float* __restrict__ x,
    const int*   __restrict__ mol_idx,
    const int*   __restrict__ iso_idx,
    const float* __restrict__ mol_embed,
    const float* __restrict__ iso_embed,
    const float* __restrict__ b1,
    const float* __restrict__ g1,  const float* __restrict__ be1,
    const float* __restrict__ b2,
    const float* __restrict__ g2,  const float* __restrict__ be2,
    const float* __restrict__ bsh2,
    const float* __restrict__ Wsh2,
    const float* __restrict__ biso1,
    const float* __restrict__ Wiso2, const float* __restrict__ biso2,
    const unsigned short* __restrict__ wsf,
    float* __restrict__ out)
{
  // LDS total ~= 39.7 KB
  __shared__ __align__(16) unsigned short pool[16896];  // 33,792 B:
      // phase A: h1-hi [64][HSTR]
      // phase B (after B4): sh_hi [64][SSTR] (17,408 B, aliases pool)
  __shared__ float ps[8][ROWS], pq[8][ROWS];            // 4096 (transposed)
  __shared__ float mu_s[ROWS], rs_s[ROWS];              // 512
  __shared__ float sp[ROWS], eo[ROWS];                  // 512
  __shared__ int   iso_s[ROWS];                         // 256
  __shared__ unsigned char slots[320];                  // 320
  __shared__ short          tile_iso[24];               // 48
  __shared__ unsigned short tile_sb[24];                // 48
  __shared__ int rcount[12], rcount2[12], roffpad[12];  // 144
  __shared__ int ntiles, nslots;                        // 8

  unsigned short (*hp)[HSTR] = (unsigned short (*)[HSTR])pool;  // h1 hi
  unsigned short* sh_hi = pool;                 // [64][SSTR] (valid after B4)

  const int t  = threadIdx.x;
  const int r0 = blockIdx.x * ROWS;
  const int l  = t & 63, w = t >> 6;         // lane, wave (8 waves)
  const int lr = l & 15, lg = l >> 4;

  const short8* wsf8 = (const short8*)wsf;
  const float*  wsc  = (const float*)(wsf + (size_t)F32_OFF * 8);
  const float*  contrib = wsc;          // [12][64]
  const float*  gtab    = wsc + 768;    // [12]

  if (t < 12) { rcount[t] = 0; rcount2[t] = 0; }
  if (t == 0) { ntiles = 4; nslots = 64; }
  if (t < 64) slots[t] = (unsigned char)t;      // shared-head tiles: identity rows
  else if (t < 320) slots[t] = 0xFF;            // pad default
  if (t < 4)  { tile_iso[t] = -1; tile_sb[t] = (unsigned short)(16 * t); }
  __syncthreads();                                    // B0

  // ---------------- phase 0: iso ids + counts -----------------------------
  if (t < ROWS) {
    int ii = iso_idx[r0 + t];
    iso_s[t] = ii;
    atomicAdd(&rcount[ii], 1);
  }
  __syncthreads();                                    // B1

  // expert-tile metadata (needs rcount); slot fill happens after B2a
  if (t < 12) {
    int c = rcount[t];
    int nsub = (c + 15) >> 4;
    if (nsub > 0) {
      int tb = atomicAdd(&ntiles, nsub);
      int sb = atomicAdd(&nslots, nsub << 4);
      roffpad[t] = sb;
      for (int s2 = 0; s2 < nsub; s2++) {
        tile_iso[tb + s2] = (short)t;
        tile_sb[tb + s2]  = (unsigned short)(sb + (s2 << 4));
      }
    }
  }

  // ---------------- layer 1 (MFMA 16x16x32): y1 = z @ W1 + b1, 2 chunks ---
  // A-frags straight from global: k-map lg0->x[0:8], lg1->x[8:16], lg2->mol_e, lg3->iso_e
  {
    const short8* w1p = wsf8 + W1F_OFF;
    short8 bh[2], bl[2];
    #pragma unroll
    for (int q = 0; q < 2; q++) {
      int nt = w * 2 + q;
      bh[q] = w1p[nt * 64 + l];
      bl[q] = w1p[(16 + nt) * 64 + l];
    }
    const int c0 = (w * 2) * 16 + lr;
    f32x2 g1p  = {g1[c0],  g1[c0 + 16]};
    f32x2 be1p = {be1[c0], be1[c0 + 16]};
    float bn0 = b1[c0], bn1 = b1[c0 + 16];

    for (int half = 0; half < 2; half++) {
      f32x4 acc[2][2];                      // only 16 regs live per chunk
      short8 zah[2], zal[2];
      #pragma unroll
      for (int mt = 0; mt < 2; mt++) {
        int row = r0 + (half * 2 + mt) * 16 + lr;
        const float* src;
        if (lg == 0)      src = x + (size_t)row * 16;
        else if (lg == 1) src = x + (size_t)row * 16 + 8;
        else if (lg == 2) src = mol_embed + mol_idx[row] * 8;
        else              src = iso_embed + iso_idx[row] * 8;
        float4 v0 = *(const float4*)src;
        float4 v1 = *(const float4*)(src + 4);
        float vv[8] = {v0.x, v0.y, v0.z, v0.w, v1.x, v1.y, v1.z, v1.w};
        u32x4 hv, lv;
        #pragma unroll
        for (int j2 = 0; j2 < 4; j2++) {
          f32x2 p = {vv[2 * j2], vv[2 * j2 + 1]};
          unsigned int h2, l2; split2(p, h2, l2);
          hv[j2] = h2; lv[j2] = l2;
        }
        zah[mt] = __builtin_bit_cast(short8, hv);
        zal[mt] = __builtin_bit_cast(short8, lv);
      }
      #pragma unroll
      for (int mt = 0; mt < 2; mt++)
        #pragma unroll
        for (int q = 0; q < 2; q++) {
          f32x4 a_ = {0.f, 0.f, 0.f, 0.f};
          a_ = __builtin_amdgcn_mfma_f32_16x16x32_bf16(zah[mt], bh[q], a_, 0, 0, 0);
          a_ = __builtin_amdgcn_mfma_f32_16x16x32_bf16(zah[mt], bl[q], a_, 0, 0, 0);
          a_ = __builtin_amdgcn_mfma_f32_16x16x32_bf16(zal[mt], bh[q], a_, 0, 0, 0);
          acc[mt][q] = a_;
        }
      #pragma unroll
      for (int mt = 0; mt < 2; mt++)
        #pragma unroll
        for (int i = 0; i < 4; i++) {
          acc[mt][0][i] += bn0; acc[mt][1][i] += bn1;
        }
      #pragma unroll
      for (int mt = 0; mt < 2; mt++)
        #pragma unroll
        for (int i = 0; i < 4; i++) {
          float sm = acc[mt][0][i] + acc[mt][1][i];
          float sq = acc[mt][0][i]*acc[mt][0][i] + acc[mt][1][i]*acc[mt][1][i];
          #pragma unroll
          for (int m = 1; m < 16; m <<= 1) { sm += __shfl_xor(sm, m); sq += __shfl_xor(sq, m); }
          if (lr == 0) { int row = (half * 2 + mt) * 16 + lg * 4 + i; ps[w][row] = sm; pq[w][row] = sq; }
        }
      __syncthreads();                                // B2a / B2c

      if (half == 0 && t < ROWS) {                    // slot fill, once
        int ii = iso_s[t];
        int pos = atomicAdd(&rcount2[ii], 1);
        slots[roffpad[ii] + pos] = (unsigned char)t;
      }
      if (t < 32) {                                   // stats for this chunk's rows
        int row = half * 32 + t;
        float su = 0.f, sq = 0.f;
        #pragma unroll
        for (int j = 0; j < 8; j++) { su += ps[j][row]; sq += pq[j][row]; }
        float mu = su * (1.0f / 256.0f);
        float var = sq * (1.0f / 256.0f) - mu * mu;
        mu_s[row] = mu; rs_s[row] = rsqrtf(var + 1e-5f);
      }
      __syncthreads();                                // B2b / B2d

      // LN1 + GELU -> h1 hi-only bf16, this chunk's rows (acc dies here)
      #pragma unroll
      for (int mt = 0; mt < 2; mt++)
        #pragma unroll
        for (int i = 0; i < 4; i++) {
          int row = (half * 2 + mt) * 16 + lg * 4 + i;
          float mu = mu_s[row], rs = rs_s[row];
          f32x2 y = {acc[mt][0][i], acc[mt][1][i]};
          f32x2 t1 = g1p * rs;
          f32x2 t2 = splat2(-mu) * t1 + be1p;
          f32x2 gg = gelu2(y * t1 + t2);
          unsigned int h2 = cvtpk_bf16(gg);
          hp[row][c0]      = (unsigned short)h2;
          hp[row][c0 + 16] = (unsigned short)(h2 >> 16);
        }
    }
  }
  __syncthreads();                                    // B3

  // ---------------- layer 2 (MFMA 16x16x32): y2 = h1_hi @ (W2h + W2l) -----
  f32x4 a2[4];
  {
    const short8* w2p = wsf8 + W2F_OFF;
    #pragma unroll
    for (int mt = 0; mt < 4; mt++) { f32x4 zf = {0.f,0.f,0.f,0.f}; a2[mt] = zf; }
    for (int ks = 0; ks < 8; ks++) {
      int k0 = ks * 32 + lg * 8;
      short8 bh = w2p[(ks * 8 + w) * 64 + l];
      short8 bl = w2p[((8 + ks) * 8 + w) * 64 + l];
      #pragma unroll
      for (int mt = 0; mt < 4; mt++) {
        short8 ah = *(const short8*)&hp[mt * 16 + lr][k0];
        a2[mt] = __builtin_amdgcn_mfma_f32_16x16x32_bf16(ah, bh, a2[mt], 0, 0, 0);
        a2[mt] = __builtin_amdgcn_mfma_f32_16x16x32_bf16(ah, bl, a2[mt], 0, 0, 0);
      }
    }
    float bn = b2[w * 16 + lr];
    f32x4 bv = {bn, bn, bn, bn};
    #pragma unroll
    for (int mt = 0; mt < 4; mt++) a2[mt] = a2[mt] + bv;
    #pragma unroll
    for (int mt = 0; mt < 4; mt++)
      #pragma unroll
      for (int i = 0; i < 4; i++) {
        float sm = a2[mt][i];
        float sq = a2[mt][i] * a2[mt][i];
        #pragma unroll
        for (int m = 1; m < 16; m <<= 1) { sm += __shfl_xor(sm, m); sq += __shfl_xor(sq, m); }
        if (lr == 0) { int row = mt * 16 + lg * 4 + i; ps[w][row] = sm; pq[w][row] = sq; }
      }
  }
  __syncthreads();                                    // B4 (all hp reads done)

  // ---------------- LN2 stats pass ----------------------------------------
  if (t < ROWS) {
    float su = 0.f, sq = 0.f;
    #pragma unroll
    for (int j = 0; j < 8; j++) { su += ps[j][t]; sq += pq[j][t]; }
    float mu = su * (1.0f / 128.0f);
    float var = sq * (1.0f / 128.0f) - mu * mu;
    mu_s[t] = mu; rs_s[t] = rsqrtf(var + 1e-5f);
  }
  __syncthreads();                                    // B4b

  // ---------------- LN2 + GELU -> shared bf16 hi plane (alias) ------------
  {
    int c0 = w * 16 + lr;
    float g2c = g2[c0], be2c = be2[c0];
    #pragma unroll
    for (int mt = 0; mt < 4; mt++)
      #pragma unroll
      for (int i2 = 0; i2 < 4; i2 += 2) {
        int row0 = mt * 16 + lg * 4 + i2;
        int row1 = row0 + 1;
        f32x2 t1 = {g2c * rs_s[row0], g2c * rs_s[row1]};
        f32x2 t2 = {be2c - mu_s[row0] * t1.x, be2c - mu_s[row1] * t1.y};
        f32x2 y = {a2[mt][i2], a2[mt][i2 + 1]};
        f32x2 gg = gelu2(y * t1 + t2);
        unsigned int h2 = cvtpk_bf16(gg);
        sh_hi[row0 * SSTR + c0] = (unsigned short)h2;
        sh_hi[row1 * SSTR + c0] = (unsigned short)(h2 >> 16);
      }
  }
  __syncthreads();                                    // B5

  // ---------------- heads: ks-outer MFMA tile loop (low pressure) ---------
  {
    float bsh2v = bsh2[0];
    int ntl = ntiles;
    for (int tt = w; tt < ntl; tt += 8) {
      int iso = tile_iso[tt];             // -1 => shared head tile
      int sb  = tile_sb[tt];
      int ar  = slots[sb + lr] & 63;      // pad (0xFF) -> row 63 reads, write-masked
      const short8* bp = (iso < 0) ? (wsf8 + WSHF_OFF) : (wsf8 + WISOF_OFF + iso * 1024);
      f32x4 c[4];
      #pragma unroll
      for (int nt = 0; nt < 4; nt++) { f32x4 zf = {0.f,0.f,0.f,0.f}; c[nt] = zf; }
      #pragma unroll
      for (int ks = 0; ks < 4; ks++) {
        short8 a_hi = *(const short8*)&sh_hi[ar * SSTR + ks * 32 + lg * 8];
        #pragma unroll
        for (int nt = 0; nt < 4; nt++) {
          short8 b = bp[(ks * 4 + nt) * 64 + l];
          c[nt] = __builtin_amdgcn_mfma_f32_16x16x32_bf16(a_hi, b, c[nt], 0, 0, 0);
        }
      }
      int rws[4];
      #pragma unroll
      for (int i = 0; i < 4; i++) rws[i] = slots[sb + lg * 4 + i];
      float accv[4];
      if (iso < 0) {
        f32x2 w01 = {Wsh2[lr], Wsh2[16 + lr]};
        f32x2 w23 = {Wsh2[32 + lr], Wsh2[48 + lr]};
        #pragma unroll
        for (int i = 0; i < 4; i++) {
          const float* cb = contrib + iso_s[rws[i]] * 64;
          f32x2 v01 = (f32x2){c[0][i], c[1][i]} + (f32x2){cb[lr], cb[16 + lr]};
          f32x2 v23 = (f32x2){c[2][i], c[3][i]} + (f32x2){cb[32 + lr], cb[48 + lr]};
          f32x2 g01 = gelu2(v01), g23 = gelu2(v23);
          float a = g01.x * w01.x;
          a = __builtin_fmaf(g01.y, w01.y, a);
          a = __builtin_fmaf(g23.x, w23.x, a);
          a = __builtin_fmaf(g23.y, w23.y, a);
          accv[i] = a;
        }
      } else {
        f32x2 b01 = {biso1[iso * 64 + lr],      biso1[iso * 64 + 16 + lr]};
        f32x2 b23 = {biso1[iso * 64 + 32 + lr], biso1[iso * 64 + 48 + lr]};
        f32x2 x01 = {Wiso2[iso * 64 + lr],      Wiso2[iso * 64 + 16 + lr]};
        f32x2 x23 = {Wiso2[iso * 64 + 32 + lr], Wiso2[iso * 64 + 48 + lr]};
        #pragma unroll
        for (int i = 0; i < 4; i++) {
          f32x2 g01 = gelu2((f32x2){c[0][i], c[1][i]} + b01);
          f32x2 g23 = gelu2((f32x2){c[2][i], c[3][i]} + b23);
          float a = g01.x * x01.x;
          a = __builtin_fmaf(g01.y, x01.y, a);
          a = __builtin_fmaf(g23.x, x23.x, a);
          a = __builtin_fmaf(g23.y, x23.y, a);
          accv[i] = a;
        }
      }
      float tail = (iso < 0) ? bsh2v : biso2[iso];
      #pragma unroll
      for (int i = 0; i < 4; i++) {
        float a = accv[i];
        a += __shfl_xor(a, 1); a += __shfl_xor(a, 2);
        a += __shfl_xor(a, 4); a += __shfl_xor(a, 8);
        if (lr == 0) {
          int r = rws[i];
          if (iso < 0) sp[r] = a + tail;
          else if (r != 0xFF) eo[r] = a + tail;
        }
      }
    }
  }
  __syncthreads();                                    // B6

  // ---------------- epilogue: gated combine -------------------------------
  if (t < ROWS) {
    int r = t;
    float gate = gtab[iso_s[r]];
    out[r0 + r] = gate * eo[r] + (1.0f - gate) * sp[r];
  }
}

extern "C" void kernel_launch(void* const* d_in, const int* in_sizes, int n_in,
                              void* d_out, int out_size, void* d_ws, size_t ws_size,
                              hipStream_t stream) {
  const float* x         = (const float*)d_in[0];
  const int*   mol_idx   = (const int*)  d_in[1];
  const int*   iso_idx   = (const int*)  d_in[2];
  const float* mol_embed = (const float*)d_in[3];
  const float* iso_embed = (const float*)d_in[4];
  const float* W1  = (const float*)d_in[5];
  const float* b1  = (const float*)d_in[6];
  const float* g1  = (const float*)d_in[7];
  const float* be1 = (const float*)d_in[8];
  const float* W2  = (const float*)d_in[9];
  const float* b2  = (const float*)d_in[10];
  const float* g2  = (const float*)d_in[11];
  const float* be2 = (const float*)d_in[12];
  const float* Wsh1 = (const float*)d_in[13];
  const float* bsh1 = (const float*)d_in[14];
  const float* Wsh2 = (const float*)d_in[15];
  const float* bsh2 = (const float*)d_in[16];
  const float* Wiso1 = (const float*)d_in[17];
  const float* biso1 = (const float*)d_in[18];
  const float* Wiso2 = (const float*)d_in[19];
  const float* biso2 = (const float*)d_in[20];
  const float* Wg = (const float*)d_in[21];
  const float* bg = (const float*)d_in[22];
  float* out = (float*)d_out;
  unsigned short* wsf = (unsigned short*)d_ws;   // needs ~380 KB

  const int B = in_sizes[0] / 16;       // 262144
  const int grid = B / ROWS;            // 4096 blocks

  hipLaunchKernelGGL(prep_frags, dim3(96), dim3(256), 0, stream,
                     W1, W2, Wsh1, bsh1, Wiso1, iso_embed, Wg, bg, wsf);
  hipLaunchKernelGGL(corr_reg_fused, dim3(grid), dim3(THREADS), 0, stream,
                     x, mol_idx, iso_idx, mol_embed, iso_embed,
                     b1, g1, be1, b2, g2, be2,
                     bsh2, Wsh2, biso1, Wiso2, biso2, wsf, out);
}

// Round 15
// 195.254 us; speedup vs baseline: 1.1067x; 1.0258x over previous
//
#include <hip/hip_runtime.h>
#include <math.h>

// CorrectionRegressor fused kernel, round 15: barrier/sync reduction.
// r14 analysis: VALU 54%, MFMA 12% -> latency/barrier-bound (erf trim = no delta).
// Change vs r14: all iso-grouping metadata (counts, tile table, slot fill) built
// by WAVE 0 with __ballot/__popcll -- wave-synchronous, no atomics, no barriers.
// Removes 2 of 11 __syncthreads (B0, B1) + atomic serialization; other waves
// start layer-1 MFMAs immediately. Everything else identical to r14 (200us).

#define THREADS 512
#define ROWS 64

typedef __attribute__((ext_vector_type(8))) short short8;
typedef __attribute__((ext_vector_type(4))) float f32x4;
typedef __attribute__((ext_vector_type(2))) float f32x2;
typedef __attribute__((ext_vector_type(4))) unsigned int u32x4;

// d_ws layout in short8 (16 B) units:
#define W2F_OFF   0        // [h2][ks8][nt8][lane64]  = 8192 frags
#define W1F_OFF   8192     // [h2][nt16][lane64]      = 2048 frags
#define WSHF_OFF  10240    // [ks4][nt4][lane64]      = 1024 frags (hi only)
#define WISOF_OFF 11264    // [iso12][ks4][nt4][lane64]= 12288 frags (hi only)
#define F32_OFF   23552    // float region: contrib[12][64], gate[12]

__device__ __forceinline__ unsigned short f2bf(float f) {   // RNE f32->bf16
  unsigned int u = __float_as_uint(f);
  return (unsigned short)((u + 0x7FFFu + ((u >> 16) & 1u)) >> 16);
}
__device__ __forceinline__ float bf2f(unsigned short b) {
  return __uint_as_float(((unsigned int)b) << 16);
}
__device__ __forceinline__ f32x2 splat2(float s) { f32x2 r = {s, s}; return r; }
__device__ __forceinline__ f32x2 abs2(f32x2 v) {
  f32x2 r; r.x = __builtin_fabsf(v.x); r.y = __builtin_fabsf(v.y); return r;
}
__device__ __forceinline__ unsigned int cvtpk_bf16(f32x2 v) {
  unsigned int r;
  asm("v_cvt_pk_bf16_f32 %0, %1, %2" : "=v"(r) : "v"(v.x), "v"(v.y));
  return r;
}
__device__ __forceinline__ void split2(f32x2 v, unsigned int& hi2, unsigned int& lo2) {
  hi2 = cvtpk_bf16(v);
  f32x2 hf;
  hf.x = __uint_as_float(hi2 << 16);
  hf.y = __uint_as_float(hi2 & 0xFFFF0000u);
  f32x2 rem = v - hf;
  lo2 = cvtpk_bf16(rem);
}
// pair GELU, erf via A&S 7.1.25 3-term (|eps|<=2.5e-5), branch-free.
__device__ __forceinline__ f32x2 gelu2(f32x2 v) {
  f32x2 x  = v * 0.70710678118654752f;
  f32x2 ax = abs2(x);
  f32x2 den = ax * 0.47047f + 1.0f;
  f32x2 t; t.x = __builtin_amdgcn_rcpf(den.x); t.y = __builtin_amdgcn_rcpf(den.y);
  f32x2 nx2 = -x * x;
  f32x2 e; e.x = __expf(nx2.x); e.y = __expf(nx2.y);
  f32x2 p = t * 0.7478556f + splat2(-0.0958798f);
  p = t * p + 0.3480242f;
  p = p * t;
  f32x2 r = splat2(1.0f) - p * e;
  r.x = __builtin_copysignf(r.x, x.x);
  r.y = __builtin_copysignf(r.y, x.y);
  f32x2 s = r * 0.5f + 0.5f;
  return v * s;
}

// ---- prep: weight fragments + per-iso tables into d_ws (r14 layout) ------
__global__ void prep_frags(const float* __restrict__ W1, const float* __restrict__ W2,
                           const float* __restrict__ Wsh1, const float* __restrict__ bsh1,
                           const float* __restrict__ Wiso1,
                           const float* __restrict__ iso_embed,
                           const float* __restrict__ Wg, const float* __restrict__ bg,
                           unsigned short* __restrict__ wsf) {
  int id = blockIdx.x * 256 + threadIdx.x;
  float* wsc = (float*)(wsf + (size_t)F32_OFF * 8);
  if (id < 8192) {                      // W2 frags hi/lo (16x16 map)
    int l = id & 63, nt = (id >> 6) & 7, ks = (id >> 9) & 7, h = id >> 12;
    int n = nt * 16 + (l & 15);
    int k0 = ks * 32 + (l >> 4) * 8;
    short8 pk;
    #pragma unroll
    for (int j = 0; j < 8; j++) {
      float v = W2[(k0 + j) * 128 + n];
      unsigned short hb = f2bf(v);
      pk[j] = (short)(h ? f2bf(v - bf2f(hb)) : hb);
    }
    *(short8*)(wsf + (size_t)id * 8) = pk;
  } else if (id < 10240) {              // W1 frags hi/lo
    int id2 = id - 8192;
    int l = id2 & 63, nt = (id2 >> 6) & 15, h = id2 >> 10;
    int n = nt * 16 + (l & 15);
    int k0 = (l >> 4) * 8;
    short8 pk;
    #pragma unroll
    for (int j = 0; j < 8; j++) {
      float v = W1[(k0 + j) * 256 + n];
      unsigned short hb = f2bf(v);
      pk[j] = (short)(h ? f2bf(v - bf2f(hb)) : hb);
    }
    *(short8*)(wsf + (size_t)id * 8) = pk;
  } else if (id < 11264) {              // Wsh1[:128] frags, hi only
    int fid = id - 10240;
    int l = fid & 63, nt = (fid >> 6) & 3, ks = fid >> 8;
    int n = nt * 16 + (l & 15);
    int k0 = ks * 32 + (l >> 4) * 8;
    short8 pk;
    #pragma unroll
    for (int j = 0; j < 8; j++) pk[j] = (short)f2bf(Wsh1[(k0 + j) * 64 + n]);
    *(short8*)(wsf + (size_t)id * 8) = pk;
  } else if (id < 23552) {              // Wiso1 frags, hi only
    int fid = id - 11264;
    int l = fid & 63, nt = (fid >> 6) & 3, ks = (fid >> 8) & 3, iso = fid >> 10;
    int n = nt * 16 + (l & 15);
    int k0 = ks * 32 + (l >> 4) * 8;
    short8 pk;
    #pragma unroll
    for (int j = 0; j < 8; j++) pk[j] = (short)f2bf(Wiso1[iso * 8192 + (k0 + j) * 64 + n]);
    *(short8*)(wsf + (size_t)id * 8) = pk;
  } else if (id < 24320) {              // contrib[i][n] = bsh1[n] + ie_i @ Wsh1[128:]
    int cid = id - 23552;
    int i = cid >> 6, n = cid & 63;
    float s = bsh1[n];
    #pragma unroll
    for (int e = 0; e < 8; e++) s += iso_embed[i * 8 + e] * Wsh1[(128 + e) * 64 + n];
    wsc[cid] = s;
  } else if (id < 24332) {              // gate[i]
    int i = id - 24320;
    float s = bg[0];
    #pragma unroll
    for (int e = 0; e < 8; e++) s += iso_embed[i * 8 + e] * Wg[e];
    wsc[768 + i] = 1.0f / (1.0f + expf(-s));
  }
}

#define HSTR 264   // h1-hi row stride (u16): 528 B, 16B-aligned rows
#define SSTR 136   // shared-plane row stride (u16): 272 B, 16B-aligned rows

__global__ __launch_bounds__(THREADS, 6)   // r11/r14's best occupancy/spill balance
void corr_reg_fused(
    const float* __restrict__ x,
    const int*   __restrict__ mol_idx,
    const int*   __restrict__ iso_idx,
    const float* __restrict__ mol_embed,
    const float* __restrict__ iso_embed,
    const float* __restrict__ b1,
    const float* __restrict__ g1,  const float* __restrict__ be1,
    const float* __restrict__ b2,
    const float* __restrict__ g2,  const float* __restrict__ be2,
    const float* __restrict__ bsh2,
    const float* __restrict__ Wsh2,
    const float* __restrict__ biso1,
    const float* __restrict__ Wiso2, const float* __restrict__ biso2,
    const unsigned short* __restrict__ wsf,
    float* __restrict__ out)
{
  // LDS total ~= 39.6 KB
  __shared__ __align__(16) unsigned short pool[16896];  // 33,792 B:
      // phase A: h1-hi [64][HSTR]
      // phase B (after B4): sh_hi [64][SSTR] (17,408 B, aliases pool)
  __shared__ float ps[8][ROWS], pq[8][ROWS];            // 4096 (transposed)
  __shared__ float mu_s[ROWS], rs_s[ROWS];              // 512
  __shared__ float sp[ROWS], eo[ROWS];                  // 512
  __shared__ int   iso_s[ROWS];                         // 256
  __shared__ unsigned char slots[320];                  // 320
  __shared__ short          tile_iso[24];               // 48
  __shared__ unsigned short tile_sb[24];                // 48
  __shared__ int ntiles;                                // 4

  unsigned short (*hp)[HSTR] = (unsigned short (*)[HSTR])pool;  // h1 hi
  unsigned short* sh_hi = pool;                 // [64][SSTR] (valid after B4)

  const int t  = threadIdx.x;
  const int r0 = blockIdx.x * ROWS;
  const int l  = t & 63, w = t >> 6;         // lane, wave (8 waves)
  const int lr = l & 15, lg = l >> 4;

  const short8* wsf8 = (const short8*)wsf;
  const float*  wsc  = (const float*)(wsf + (size_t)F32_OFF * 8);
  const float*  contrib = wsc;          // [12][64]
  const float*  gtab    = wsc + 768;    // [12]

  // ---------------- wave-0 ballot metadata (no atomics, no barriers) ------
  // All consumed after B5 (heads) / B6 (epilogue); many barriers in between.
  if (w == 0) {
    int ii = iso_idx[r0 + l];
    iso_s[l] = ii;
    slots[l] = (unsigned char)l;                 // shared-head identity tiles
    #pragma unroll
    for (int p = 1; p < 5; p++) slots[l + p * 64] = (unsigned char)0xFF;
    if (l < 4) { tile_iso[l] = -1; tile_sb[l] = (unsigned short)(16 * l); }
    int ntl = 4, sb = 64, myslot = -1;
    #pragma unroll
    for (int i = 0; i < 12; i++) {
      unsigned long long m = __ballot(ii == i);
      int c = __popcll(m);
      int nsub = (c + 15) >> 4;
      if (ii == i) myslot = sb + __popcll(m & ((1ull << l) - 1ull));
      if (l < nsub) {
        tile_iso[ntl + l] = (short)i;
        tile_sb[ntl + l]  = (unsigned short)(sb + (l << 4));
      }
      ntl += nsub; sb += nsub << 4;
    }
    if (myslot >= 0) slots[myslot] = (unsigned char)l;
    if (l == 0) ntiles = ntl;
  }

  // ---------------- layer 1 (MFMA 16x16x32): y1 = z @ W1 + b1, 2 chunks ---
  // A-frags straight from global: k-map lg0->x[0:8], lg1->x[8:16], lg2->mol_e, lg3->iso_e
  {
    const short8* w1p = wsf8 + W1F_OFF;
    short8 bh[2], bl[2];
    #pragma unroll
    for (int q = 0; q < 2; q++) {
      int nt = w * 2 + q;
      bh[q] = w1p[nt * 64 + l];
      bl[q] = w1p[(16 + nt) * 64 + l];
    }
    const int c0 = (w * 2) * 16 + lr;
    f32x2 g1p  = {g1[c0],  g1[c0 + 16]};
    f32x2 be1p = {be1[c0], be1[c0 + 16]};
    float bn0 = b1[c0], bn1 = b1[c0 + 16];

    for (int half = 0; half < 2; half++) {
      f32x4 acc[2][2];                      // only 16 regs live per chunk
      short8 zah[2], zal[2];
      #pragma unroll
      for (int mt = 0; mt < 2; mt++) {
        int row = r0 + (half * 2 + mt) * 16 + lr;
        const float* src;
        if (lg == 0)      src = x + (size_t)row * 16;
        else if (lg == 1) src = x + (size_t)row * 16 + 8;
        else if (lg == 2) src = mol_embed + mol_idx[row] * 8;
        else              src = iso_embed + iso_idx[row] * 8;
        float4 v0 = *(const float4*)src;
        float4 v1 = *(const float4*)(src + 4);
        float vv[8] = {v0.x, v0.y, v0.z, v0.w, v1.x, v1.y, v1.z, v1.w};
        u32x4 hv, lv;
        #pragma unroll
        for (int j2 = 0; j2 < 4; j2++) {
          f32x2 p = {vv[2 * j2], vv[2 * j2 + 1]};
          unsigned int h2, l2; split2(p, h2, l2);
          hv[j2] = h2; lv[j2] = l2;
        }
        zah[mt] = __builtin_bit_cast(short8, hv);
        zal[mt] = __builtin_bit_cast(short8, lv);
      }
      #pragma unroll
      for (int mt = 0; mt < 2; mt++)
        #pragma unroll
        for (int q = 0; q < 2; q++) {
          f32x4 a_ = {0.f, 0.f, 0.f, 0.f};
          a_ = __builtin_amdgcn_mfma_f32_16x16x32_bf16(zah[mt], bh[q], a_, 0, 0, 0);
          a_ = __builtin_amdgcn_mfma_f32_16x16x32_bf16(zah[mt], bl[q], a_, 0, 0, 0);
          a_ = __builtin_amdgcn_mfma_f32_16x16x32_bf16(zal[mt], bh[q], a_, 0, 0, 0);
          acc[mt][q] = a_;
        }
      #pragma unroll
      for (int mt = 0; mt < 2; mt++)
        #pragma unroll
        for (int i = 0; i < 4; i++) {
          acc[mt][0][i] += bn0; acc[mt][1][i] += bn1;
        }
      #pragma unroll
      for (int mt = 0; mt < 2; mt++)
        #pragma unroll
        for (int i = 0; i < 4; i++) {
          float sm = acc[mt][0][i] + acc[mt][1][i];
          float sq = acc[mt][0][i]*acc[mt][0][i] + acc[mt][1][i]*acc[mt][1][i];
          #pragma unroll
          for (int m = 1; m < 16; m <<= 1) { sm += __shfl_xor(sm, m); sq += __shfl_xor(sq, m); }
          if (lr == 0) { int row = (half * 2 + mt) * 16 + lg * 4 + i; ps[w][row] = sm; pq[w][row] = sq; }
        }
      __syncthreads();                                // B2a / B2c

      if (t < 32) {                                   // stats for this chunk's rows
        int row = half * 32 + t;
        float su = 0.f, sq = 0.f;
        #pragma unroll
        for (int j = 0; j < 8; j++) { su += ps[j][row]; sq += pq[j][row]; }
        float mu = su * (1.0f / 256.0f);
        float var = sq * (1.0f / 256.0f) - mu * mu;
        mu_s[row] = mu; rs_s[row] = rsqrtf(var + 1e-5f);
      }
      __syncthreads();                                // B2b / B2d

      // LN1 + GELU -> h1 hi-only bf16, this chunk's rows (acc dies here)
      #pragma unroll
      for (int mt = 0; mt < 2; mt++)
        #pragma unroll
        for (int i = 0; i < 4; i++) {
          int row = (half * 2 + mt) * 16 + lg * 4 + i;
          float mu = mu_s[row], rs = rs_s[row];
          f32x2 y = {acc[mt][0][i], acc[mt][1][i]};
          f32x2 t1 = g1p * rs;
          f32x2 t2 = splat2(-mu) * t1 + be1p;
          f32x2 gg = gelu2(y * t1 + t2);
          unsigned int h2 = cvtpk_bf16(gg);
          hp[row][c0]      = (unsigned short)h2;
          hp[row][c0 + 16] = (unsigned short)(h2 >> 16);
        }
    }
  }
  __syncthreads();                                    // B3

  // ---------------- layer 2 (MFMA 16x16x32): y2 = h1_hi @ (W2h + W2l) -----
  f32x4 a2[4];
  {
    const short8* w2p = wsf8 + W2F_OFF;
    #pragma unroll
    for (int mt = 0; mt < 4; mt++) { f32x4 zf = {0.f,0.f,0.f,0.f}; a2[mt] = zf; }
    for (int ks = 0; ks < 8; ks++) {
      int k0 = ks * 32 + lg * 8;
      short8 bh = w2p[(ks * 8 + w) * 64 + l];
      short8 bl = w2p[((8 + ks) * 8 + w) * 64 + l];
      #pragma unroll
      for (int mt = 0; mt < 4; mt++) {
        short8 ah = *(const short8*)&hp[mt * 16 + lr][k0];
        a2[mt] = __builtin_amdgcn_mfma_f32_16x16x32_bf16(ah, bh, a2[mt], 0, 0, 0);
        a2[mt] = __builtin_amdgcn_mfma_f32_16x16x32_bf16(ah, bl, a2[mt], 0, 0, 0);
      }
    }
    float bn = b2[w * 16 + lr];
    f32x4 bv = {bn, bn, bn, bn};
    #pragma unroll
    for (int mt = 0; mt < 4; mt++) a2[mt] = a2[mt] + bv;
    #pragma unroll
    for (int mt = 0; mt < 4; mt++)
      #pragma unroll
      for (int i = 0; i < 4; i++) {
        float sm = a2[mt][i];
        float sq = a2[mt][i] * a2[mt][i];
        #pragma unroll
        for (int m = 1; m < 16; m <<= 1) { sm += __shfl_xor(sm, m); sq += __shfl_xor(sq, m); }
        if (lr == 0) { int row = mt * 16 + lg * 4 + i; ps[w][row] = sm; pq[w][row] = sq; }
      }
  }
  __syncthreads();                                    // B4 (all hp reads done)

  // ---------------- LN2 stats pass ----------------------------------------
  if (t < ROWS) {
    float su = 0.f, sq = 0.f;
    #pragma unroll
    for (int j = 0; j < 8; j++) { su += ps[j][t]; sq += pq[j][t]; }
    float mu = su * (1.0f / 128.0f);
    float var = sq * (1.0f / 128.0f) - mu * mu;
    mu_s[t] = mu; rs_s[t] = rsqrtf(var + 1e-5f);
  }
  __syncthreads();                                    // B4b

  // ---------------- LN2 + GELU -> shared bf16 hi plane (alias) ------------
  {
    int c0 = w * 16 + lr;
    float g2c = g2[c0], be2c = be2[c0];
    #pragma unroll
    for (int mt = 0; mt < 4; mt++)
      #pragma unroll
      for (int i2 = 0; i2 < 4; i2 += 2) {
        int row0 = mt * 16 + lg * 4 + i2;
        int row1 = row0 + 1;
        f32x2 t1 = {g2c * rs_s[row0], g2c * rs_s[row1]};
        f32x2 t2 = {be2c - mu_s[row0] * t1.x, be2c - mu_s[row1] * t1.y};
        f32x2 y = {a2[mt][i2], a2[mt][i2 + 1]};
        f32x2 gg = gelu2(y * t1 + t2);
        unsigned int h2 = cvtpk_bf16(gg);
        sh_hi[row0 * SSTR + c0] = (unsigned short)h2;
        sh_hi[row1 * SSTR + c0] = (unsigned short)(h2 >> 16);
      }
  }
  __syncthreads();                                    // B5

  // ---------------- heads: ks-outer MFMA tile loop (low pressure) ---------
  {
    float bsh2v = bsh2[0];
    int ntl = ntiles;
    for (int tt = w; tt < ntl; tt += 8) {
      int iso = tile_iso[tt];             // -1 => shared head tile
      int sb  = tile_sb[tt];
      int ar  = slots[sb + lr] & 63;      // pad (0xFF) -> row 63 reads, write-masked
      const short8* bp = (iso < 0) ? (wsf8 + WSHF_OFF) : (wsf8 + WISOF_OFF + iso * 1024);
      f32x4 c[4];
      #pragma unroll
      for (int nt = 0; nt < 4; nt++) { f32x4 zf = {0.f,0.f,0.f,0.f}; c[nt] = zf; }
      #pragma unroll
      for (int ks = 0; ks < 4; ks++) {
        short8 a_hi = *(const short8*)&sh_hi[ar * SSTR + ks * 32 + lg * 8];
        #pragma unroll
        for (int nt = 0; nt < 4; nt++) {
          short8 b = bp[(ks * 4 + nt) * 64 + l];
          c[nt] = __builtin_amdgcn_mfma_f32_16x16x32_bf16(a_hi, b, c[nt], 0, 0, 0);
        }
      }
      int rws[4];
      #pragma unroll
      for (int i = 0; i < 4; i++) rws[i] = slots[sb + lg * 4 + i];
      float accv[4];
      if (iso < 0) {
        f32x2 w01 = {Wsh2[lr], Wsh2[16 + lr]};
        f32x2 w23 = {Wsh2[32 + lr], Wsh2[48 + lr]};
        #pragma unroll
        for (int i = 0; i < 4; i++) {
          const float* cb = contrib + iso_s[rws[i]] * 64;
          f32x2 v01 = (f32x2){c[0][i], c[1][i]} + (f32x2){cb[lr], cb[16 + lr]};
          f32x2 v23 = (f32x2){c[2][i], c[3][i]} + (f32x2){cb[32 + lr], cb[48 + lr]};
          f32x2 g01 = gelu2(v01), g23 = gelu2(v23);
          float a = g01.x * w01.x;
          a = __builtin_fmaf(g01.y, w01.y, a);
          a = __builtin_fmaf(g23.x, w23.x, a);
          a = __builtin_fmaf(g23.y, w23.y, a);
          accv[i] = a;
        }
      } else {
        f32x2 b01 = {biso1[iso * 64 + lr],      biso1[iso * 64 + 16 + lr]};
        f32x2 b23 = {biso1[iso * 64 + 32 + lr], biso1[iso * 64 + 48 + lr]};
        f32x2 x01 = {Wiso2[iso * 64 + lr],      Wiso2[iso * 64 + 16 + lr]};
        f32x2 x23 = {Wiso2[iso * 64 + 32 + lr], Wiso2[iso * 64 + 48 + lr]};
        #pragma unroll
        for (int i = 0; i < 4; i++) {
          f32x2 g01 = gelu2((f32x2){c[0][i], c[1][i]} + b01);
          f32x2 g23 = gelu2((f32x2){c[2][i], c[3][i]} + b23);
          float a = g01.x * x01.x;
          a = __builtin_fmaf(g01.y, x01.y, a);
          a = __builtin_fmaf(g23.x, x23.x, a);
          a = __builtin_fmaf(g23.y, x23.y, a);
          accv[i] = a;
        }
      }
      float tail = (iso < 0) ? bsh2v : biso2[iso];
      #pragma unroll
      for (int i = 0; i < 4; i++) {
        float a = accv[i];
        a += __shfl_xor(a, 1); a += __shfl_xor(a, 2);
        a += __shfl_xor(a, 4); a += __shfl_xor(a, 8);
        if (lr == 0) {
          int r = rws[i];
          if (iso < 0) sp[r] = a + tail;
          else if (r != 0xFF) eo[r] = a + tail;
        }
      }
    }
  }
  __syncthreads();                                    // B6

  // ---------------- epilogue: gated combine -------------------------------
  if (t < ROWS) {
    int r = t;
    float gate = gtab[iso_s[r]];
    out[r0 + r] = gate * eo[r] + (1.0f - gate) * sp[r];
  }
}

extern "C" void kernel_launch(void* const* d_in, const int* in_sizes, int n_in,
                              void* d_out, int out_size, void* d_ws, size_t ws_size,
                              hipStream_t stream) {
  const float* x         = (const float*)d_in[0];
  const int*   mol_idx   = (const int*)  d_in[1];
  const int*   iso_idx   = (const int*)  d_in[2];
  const float* mol_embed = (const float*)d_in[3];
  const float* iso_embed = (const float*)d_in[4];
  const float* W1  = (const float*)d_in[5];
  const float* b1  = (const float*)d_in[6];
  const float* g1  = (const float*)d_in[7];
  const float* be1 = (const float*)d_in[8];
  const float* W2  = (const float*)d_in[9];
  const float* b2  = (const float*)d_in[10];
  const float* g2  = (const float*)d_in[11];
  const float* be2 = (const float*)d_in[12];
  const float* Wsh1 = (const float*)d_in[13];
  const float* bsh1 = (const float*)d_in[14];
  const float* Wsh2 = (const float*)d_in[15];
  const float* bsh2 = (const float*)d_in[16];
  const float* Wiso1 = (const float*)d_in[17];
  const float* biso1 = (const float*)d_in[18];
  const float* Wiso2 = (const float*)d_in[19];
  const float* biso2 = (const float*)d_in[20];
  const float* Wg = (const float*)d_in[21];
  const float* bg = (const float*)d_in[22];
  float* out = (float*)d_out;
  unsigned short* wsf = (unsigned short*)d_ws;   // needs ~380 KB

  const int B = in_sizes[0] / 16;       // 262144
  const int grid = B / ROWS;            // 4096 blocks

  hipLaunchKernelGGL(prep_frags, dim3(96), dim3(256), 0, stream,
                     W1, W2, Wsh1, bsh1, Wiso1, iso_embed, Wg, bg, wsf);
  hipLaunchKernelGGL(corr_reg_fused, dim3(grid), dim3(THREADS), 0, stream,
                     x, mol_idx, iso_idx, mol_embed, iso_embed,
                     b1, g1, be1, b2, g2, be2,
                     bsh2, Wsh2, biso1, Wiso2, biso2, wsf, out);
}

// Round 16
// 188.279 us; speedup vs baseline: 1.1477x; 1.0370x over previous
//
#include <hip/hip_runtime.h>
#include <math.h>

// CorrectionRegressor fused kernel, round 16: layer-2 B-lo dropped.
// r15: spills gone (ballot metadata), 195us, VALU 56% / MFMA 13% -> latency-
// structure bound. Last >=2% lever: layer-2 product A_hi x (B_hi + B_lo) ->
// A_hi x B_hi only. Error budget: +~4e-4 at output (absmax 9.8e-4 -> ~1.3e-3,
// threshold 4.55e-3). Halves layer-2 MFMAs (64->32/wave), -8 loads/wave.
// Everything else identical to r15.

#define THREADS 512
#define ROWS 64

typedef __attribute__((ext_vector_type(8))) short short8;
typedef __attribute__((ext_vector_type(4))) float f32x4;
typedef __attribute__((ext_vector_type(2))) float f32x2;
typedef __attribute__((ext_vector_type(4))) unsigned int u32x4;

// d_ws layout in short8 (16 B) units:
#define W2F_OFF   0        // [h2][ks8][nt8][lane64]  = 8192 frags (lo plane now unused)
#define W1F_OFF   8192     // [h2][nt16][lane64]      = 2048 frags
#define WSHF_OFF  10240    // [ks4][nt4][lane64]      = 1024 frags (hi only)
#define WISOF_OFF 11264    // [iso12][ks4][nt4][lane64]= 12288 frags (hi only)
#define F32_OFF   23552    // float region: contrib[12][64], gate[12]

__device__ __forceinline__ unsigned short f2bf(float f) {   // RNE f32->bf16
  unsigned int u = __float_as_uint(f);
  return (unsigned short)((u + 0x7FFFu + ((u >> 16) & 1u)) >> 16);
}
__device__ __forceinline__ float bf2f(unsigned short b) {
  return __uint_as_float(((unsigned int)b) << 16);
}
__device__ __forceinline__ f32x2 splat2(float s) { f32x2 r = {s, s}; return r; }
__device__ __forceinline__ f32x2 abs2(f32x2 v) {
  f32x2 r; r.x = __builtin_fabsf(v.x); r.y = __builtin_fabsf(v.y); return r;
}
__device__ __forceinline__ unsigned int cvtpk_bf16(f32x2 v) {
  unsigned int r;
  asm("v_cvt_pk_bf16_f32 %0, %1, %2" : "=v"(r) : "v"(v.x), "v"(v.y));
  return r;
}
__device__ __forceinline__ void split2(f32x2 v, unsigned int& hi2, unsigned int& lo2) {
  hi2 = cvtpk_bf16(v);
  f32x2 hf;
  hf.x = __uint_as_float(hi2 << 16);
  hf.y = __uint_as_float(hi2 & 0xFFFF0000u);
  f32x2 rem = v - hf;
  lo2 = cvtpk_bf16(rem);
}
// pair GELU, erf via A&S 7.1.25 3-term (|eps|<=2.5e-5), branch-free.
__device__ __forceinline__ f32x2 gelu2(f32x2 v) {
  f32x2 x  = v * 0.70710678118654752f;
  f32x2 ax = abs2(x);
  f32x2 den = ax * 0.47047f + 1.0f;
  f32x2 t; t.x = __builtin_amdgcn_rcpf(den.x); t.y = __builtin_amdgcn_rcpf(den.y);
  f32x2 nx2 = -x * x;
  f32x2 e; e.x = __expf(nx2.x); e.y = __expf(nx2.y);
  f32x2 p = t * 0.7478556f + splat2(-0.0958798f);
  p = t * p + 0.3480242f;
  p = p * t;
  f32x2 r = splat2(1.0f) - p * e;
  r.x = __builtin_copysignf(r.x, x.x);
  r.y = __builtin_copysignf(r.y, x.y);
  f32x2 s = r * 0.5f + 0.5f;
  return v * s;
}

// ---- prep: weight fragments + per-iso tables into d_ws (r15 layout) ------
__global__ void prep_frags(const float* __restrict__ W1, const float* __restrict__ W2,
                           const float* __restrict__ Wsh1, const float* __restrict__ bsh1,
                           const float* __restrict__ Wiso1,
                           const float* __restrict__ iso_embed,
                           const float* __restrict__ Wg, const float* __restrict__ bg,
                           unsigned short* __restrict__ wsf) {
  int id = blockIdx.x * 256 + threadIdx.x;
  float* wsc = (float*)(wsf + (size_t)F32_OFF * 8);
  if (id < 8192) {                      // W2 frags hi/lo (lo retained, unread)
    int l = id & 63, nt = (id >> 6) & 7, ks = (id >> 9) & 7, h = id >> 12;
    int n = nt * 16 + (l & 15);
    int k0 = ks * 32 + (l >> 4) * 8;
    short8 pk;
    #pragma unroll
    for (int j = 0; j < 8; j++) {
      float v = W2[(k0 + j) * 128 + n];
      unsigned short hb = f2bf(v);
      pk[j] = (short)(h ? f2bf(v - bf2f(hb)) : hb);
    }
    *(short8*)(wsf + (size_t)id * 8) = pk;
  } else if (id < 10240) {              // W1 frags hi/lo
    int id2 = id - 8192;
    int l = id2 & 63, nt = (id2 >> 6) & 15, h = id2 >> 10;
    int n = nt * 16 + (l & 15);
    int k0 = (l >> 4) * 8;
    short8 pk;
    #pragma unroll
    for (int j = 0; j < 8; j++) {
      float v = W1[(k0 + j) * 256 + n];
      unsigned short hb = f2bf(v);
      pk[j] = (short)(h ? f2bf(v - bf2f(hb)) : hb);
    }
    *(short8*)(wsf + (size_t)id * 8) = pk;
  } else if (id < 11264) {              // Wsh1[:128] frags, hi only
    int fid = id - 10240;
    int l = fid & 63, nt = (fid >> 6) & 3, ks = fid >> 8;
    int n = nt * 16 + (l & 15);
    int k0 = ks * 32 + (l >> 4) * 8;
    short8 pk;
    #pragma unroll
    for (int j = 0; j < 8; j++) pk[j] = (short)f2bf(Wsh1[(k0 + j) * 64 + n]);
    *(short8*)(wsf + (size_t)id * 8) = pk;
  } else if (id < 23552) {              // Wiso1 frags, hi only
    int fid = id - 11264;
    int l = fid & 63, nt = (fid >> 6) & 3, ks = (fid >> 8) & 3, iso = fid >> 10;
    int n = nt * 16 + (l & 15);
    int k0 = ks * 32 + (l >> 4) * 8;
    short8 pk;
    #pragma unroll
    for (int j = 0; j < 8; j++) pk[j] = (short)f2bf(Wiso1[iso * 8192 + (k0 + j) * 64 + n]);
    *(short8*)(wsf + (size_t)id * 8) = pk;
  } else if (id < 24320) {              // contrib[i][n] = bsh1[n] + ie_i @ Wsh1[128:]
    int cid = id - 23552;
    int i = cid >> 6, n = cid & 63;
    float s = bsh1[n];
    #pragma unroll
    for (int e = 0; e < 8; e++) s += iso_embed[i * 8 + e] * Wsh1[(128 + e) * 64 + n];
    wsc[cid] = s;
  } else if (id < 24332) {              // gate[i]
    int i = id - 24320;
    float s = bg[0];
    #pragma unroll
    for (int e = 0; e < 8; e++) s += iso_embed[i * 8 + e] * Wg[e];
    wsc[768 + i] = 1.0f / (1.0f + expf(-s));
  }
}

#define HSTR 264   // h1-hi row stride (u16): 528 B, 16B-aligned rows
#define SSTR 136   // shared-plane row stride (u16): 272 B, 16B-aligned rows

__global__ __launch_bounds__(THREADS, 6)
void corr_reg_fused(
    const float* __restrict__ x,
    const int*   __restrict__ mol_idx,
    const int*   __restrict__ iso_idx,
    const float* __restrict__ mol_embed,
    const float* __restrict__ iso_embed,
    const float* __restrict__ b1,
    const float* __restrict__ g1,  const float* __restrict__ be1,
    const float* __restrict__ b2,
    const float* __restrict__ g2,  const float* __restrict__ be2,
    const float* __restrict__ bsh2,
    const float* __restrict__ Wsh2,
    const float* __restrict__ biso1,
    const float* __restrict__ Wiso2, const float* __restrict__ biso2,
    const unsigned short* __restrict__ wsf,
    float* __restrict__ out)
{
  // LDS total ~= 39.6 KB
  __shared__ __align__(16) unsigned short pool[16896];  // 33,792 B:
      // phase A: h1-hi [64][HSTR]
      // phase B (after B4): sh_hi [64][SSTR] (17,408 B, aliases pool)
  __shared__ float ps[8][ROWS], pq[8][ROWS];            // 4096 (transposed)
  __shared__ float mu_s[ROWS], rs_s[ROWS];              // 512
  __shared__ float sp[ROWS], eo[ROWS];                  // 512
  __shared__ int   iso_s[ROWS];                         // 256
  __shared__ unsigned char slots[320];                  // 320
  __shared__ short          tile_iso[24];               // 48
  __shared__ unsigned short tile_sb[24];                // 48
  __shared__ int ntiles;                                // 4

  unsigned short (*hp)[HSTR] = (unsigned short (*)[HSTR])pool;  // h1 hi
  unsigned short* sh_hi = pool;                 // [64][SSTR] (valid after B4)

  const int t  = threadIdx.x;
  const int r0 = blockIdx.x * ROWS;
  const int l  = t & 63, w = t >> 6;         // lane, wave (8 waves)
  const int lr = l & 15, lg = l >> 4;

  const short8* wsf8 = (const short8*)wsf;
  const float*  wsc  = (const float*)(wsf + (size_t)F32_OFF * 8);
  const float*  contrib = wsc;          // [12][64]
  const float*  gtab    = wsc + 768;    // [12]

  // ---------------- wave-0 ballot metadata (no atomics, no barriers) ------
  if (w == 0) {
    int ii = iso_idx[r0 + l];
    iso_s[l] = ii;
    slots[l] = (unsigned char)l;                 // shared-head identity tiles
    #pragma unroll
    for (int p = 1; p < 5; p++) slots[l + p * 64] = (unsigned char)0xFF;
    if (l < 4) { tile_iso[l] = -1; tile_sb[l] = (unsigned short)(16 * l); }
    int ntl = 4, sb = 64, myslot = -1;
    #pragma unroll
    for (int i = 0; i < 12; i++) {
      unsigned long long m = __ballot(ii == i);
      int c = __popcll(m);
      int nsub = (c + 15) >> 4;
      if (ii == i) myslot = sb + __popcll(m & ((1ull << l) - 1ull));
      if (l < nsub) {
        tile_iso[ntl + l] = (short)i;
        tile_sb[ntl + l]  = (unsigned short)(sb + (l << 4));
      }
      ntl += nsub; sb += nsub << 4;
    }
    if (myslot >= 0) slots[myslot] = (unsigned char)l;
    if (l == 0) ntiles = ntl;
  }

  // ---------------- layer 1 (MFMA 16x16x32): y1 = z @ W1 + b1, 2 chunks ---
  {
    const short8* w1p = wsf8 + W1F_OFF;
    short8 bh[2], bl[2];
    #pragma unroll
    for (int q = 0; q < 2; q++) {
      int nt = w * 2 + q;
      bh[q] = w1p[nt * 64 + l];
      bl[q] = w1p[(16 + nt) * 64 + l];
    }
    const int c0 = (w * 2) * 16 + lr;
    f32x2 g1p  = {g1[c0],  g1[c0 + 16]};
    f32x2 be1p = {be1[c0], be1[c0 + 16]};
    float bn0 = b1[c0], bn1 = b1[c0 + 16];

    for (int half = 0; half < 2; half++) {
      f32x4 acc[2][2];
      short8 zah[2], zal[2];
      #pragma unroll
      for (int mt = 0; mt < 2; mt++) {
        int row = r0 + (half * 2 + mt) * 16 + lr;
        const float* src;
        if (lg == 0)      src = x + (size_t)row * 16;
        else if (lg == 1) src = x + (size_t)row * 16 + 8;
        else if (lg == 2) src = mol_embed + mol_idx[row] * 8;
        else              src = iso_embed + iso_idx[row] * 8;
        float4 v0 = *(const float4*)src;
        float4 v1 = *(const float4*)(src + 4);
        float vv[8] = {v0.x, v0.y, v0.z, v0.w, v1.x, v1.y, v1.z, v1.w};
        u32x4 hv, lv;
        #pragma unroll
        for (int j2 = 0; j2 < 4; j2++) {
          f32x2 p = {vv[2 * j2], vv[2 * j2 + 1]};
          unsigned int h2, l2; split2(p, h2, l2);
          hv[j2] = h2; lv[j2] = l2;
        }
        zah[mt] = __builtin_bit_cast(short8, hv);
        zal[mt] = __builtin_bit_cast(short8, lv);
      }
      #pragma unroll
      for (int mt = 0; mt < 2; mt++)
        #pragma unroll
        for (int q = 0; q < 2; q++) {
          f32x4 a_ = {0.f, 0.f, 0.f, 0.f};
          a_ = __builtin_amdgcn_mfma_f32_16x16x32_bf16(zah[mt], bh[q], a_, 0, 0, 0);
          a_ = __builtin_amdgcn_mfma_f32_16x16x32_bf16(zah[mt], bl[q], a_, 0, 0, 0);
          a_ = __builtin_amdgcn_mfma_f32_16x16x32_bf16(zal[mt], bh[q], a_, 0, 0, 0);
          acc[mt][q] = a_;
        }
      #pragma unroll
      for (int mt = 0; mt < 2; mt++)
        #pragma unroll
        for (int i = 0; i < 4; i++) {
          acc[mt][0][i] += bn0; acc[mt][1][i] += bn1;
        }
      #pragma unroll
      for (int mt = 0; mt < 2; mt++)
        #pragma unroll
        for (int i = 0; i < 4; i++) {
          float sm = acc[mt][0][i] + acc[mt][1][i];
          float sq = acc[mt][0][i]*acc[mt][0][i] + acc[mt][1][i]*acc[mt][1][i];
          #pragma unroll
          for (int m = 1; m < 16; m <<= 1) { sm += __shfl_xor(sm, m); sq += __shfl_xor(sq, m); }
          if (lr == 0) { int row = (half * 2 + mt) * 16 + lg * 4 + i; ps[w][row] = sm; pq[w][row] = sq; }
        }
      __syncthreads();                                // B2a / B2c

      if (t < 32) {                                   // stats for this chunk's rows
        int row = half * 32 + t;
        float su = 0.f, sq = 0.f;
        #pragma unroll
        for (int j = 0; j < 8; j++) { su += ps[j][row]; sq += pq[j][row]; }
        float mu = su * (1.0f / 256.0f);
        float var = sq * (1.0f / 256.0f) - mu * mu;
        mu_s[row] = mu; rs_s[row] = rsqrtf(var + 1e-5f);
      }
      __syncthreads();                                // B2b / B2d

      // LN1 + GELU -> h1 hi-only bf16, this chunk's rows (acc dies here)
      #pragma unroll
      for (int mt = 0; mt < 2; mt++)
        #pragma unroll
        for (int i = 0; i < 4; i++) {
          int row = (half * 2 + mt) * 16 + lg * 4 + i;
          float mu = mu_s[row], rs = rs_s[row];
          f32x2 y = {acc[mt][0][i], acc[mt][1][i]};
          f32x2 t1 = g1p * rs;
          f32x2 t2 = splat2(-mu) * t1 + be1p;
          f32x2 gg = gelu2(y * t1 + t2);
          unsigned int h2 = cvtpk_bf16(gg);
          hp[row][c0]      = (unsigned short)h2;
          hp[row][c0 + 16] = (unsigned short)(h2 >> 16);
        }
    }
  }
  __syncthreads();                                    // B3

  // ---------------- layer 2 (MFMA 16x16x32): y2 = h1_hi @ W2_hi + b2 ------
  f32x4 a2[4];
  {
    const short8* w2p = wsf8 + W2F_OFF;
    #pragma unroll
    for (int mt = 0; mt < 4; mt++) { f32x4 zf = {0.f,0.f,0.f,0.f}; a2[mt] = zf; }
    for (int ks = 0; ks < 8; ks++) {
      int k0 = ks * 32 + lg * 8;
      short8 bh = w2p[(ks * 8 + w) * 64 + l];
      #pragma unroll
      for (int mt = 0; mt < 4; mt++) {
        short8 ah = *(const short8*)&hp[mt * 16 + lr][k0];
        a2[mt] = __builtin_amdgcn_mfma_f32_16x16x32_bf16(ah, bh, a2[mt], 0, 0, 0);
      }
    }
    float bn = b2[w * 16 + lr];
    f32x4 bv = {bn, bn, bn, bn};
    #pragma unroll
    for (int mt = 0; mt < 4; mt++) a2[mt] = a2[mt] + bv;
    #pragma unroll
    for (int mt = 0; mt < 4; mt++)
      #pragma unroll
      for (int i = 0; i < 4; i++) {
        float sm = a2[mt][i];
        float sq = a2[mt][i] * a2[mt][i];
        #pragma unroll
        for (int m = 1; m < 16; m <<= 1) { sm += __shfl_xor(sm, m); sq += __shfl_xor(sq, m); }
        if (lr == 0) { int row = mt * 16 + lg * 4 + i; ps[w][row] = sm; pq[w][row] = sq; }
      }
  }
  __syncthreads();                                    // B4 (all hp reads done)

  // ---------------- LN2 stats pass ----------------------------------------
  if (t < ROWS) {
    float su = 0.f, sq = 0.f;
    #pragma unroll
    for (int j = 0; j < 8; j++) { su += ps[j][t]; sq += pq[j][t]; }
    float mu = su * (1.0f / 128.0f);
    float var = sq * (1.0f / 128.0f) - mu * mu;
    mu_s[t] = mu; rs_s[t] = rsqrtf(var + 1e-5f);
  }
  __syncthreads();                                    // B4b

  // ---------------- LN2 + GELU -> shared bf16 hi plane (alias) ------------
  {
    int c0 = w * 16 + lr;
    float g2c = g2[c0], be2c = be2[c0];
    #pragma unroll
    for (int mt = 0; mt < 4; mt++)
      #pragma unroll
      for (int i2 = 0; i2 < 4; i2 += 2) {
        int row0 = mt * 16 + lg * 4 + i2;
        int row1 = row0 + 1;
        f32x2 t1 = {g2c * rs_s[row0], g2c * rs_s[row1]};
        f32x2 t2 = {be2c - mu_s[row0] * t1.x, be2c - mu_s[row1] * t1.y};
        f32x2 y = {a2[mt][i2], a2[mt][i2 + 1]};
        f32x2 gg = gelu2(y * t1 + t2);
        unsigned int h2 = cvtpk_bf16(gg);
        sh_hi[row0 * SSTR + c0] = (unsigned short)h2;
        sh_hi[row1 * SSTR + c0] = (unsigned short)(h2 >> 16);
      }
  }
  __syncthreads();                                    // B5

  // ---------------- heads: ks-outer MFMA tile loop (low pressure) ---------
  {
    float bsh2v = bsh2[0];
    int ntl = ntiles;
    for (int tt = w; tt < ntl; tt += 8) {
      int iso = tile_iso[tt];             // -1 => shared head tile
      int sb  = tile_sb[tt];
      int ar  = slots[sb + lr] & 63;      // pad (0xFF) -> row 63 reads, write-masked
      const short8* bp = (iso < 0) ? (wsf8 + WSHF_OFF) : (wsf8 + WISOF_OFF + iso * 1024);
      f32x4 c[4];
      #pragma unroll
      for (int nt = 0; nt < 4; nt++) { f32x4 zf = {0.f,0.f,0.f,0.f}; c[nt] = zf; }
      #pragma unroll
      for (int ks = 0; ks < 4; ks++) {
        short8 a_hi = *(const short8*)&sh_hi[ar * SSTR + ks * 32 + lg * 8];
        #pragma unroll
        for (int nt = 0; nt < 4; nt++) {
          short8 b = bp[(ks * 4 + nt) * 64 + l];
          c[nt] = __builtin_amdgcn_mfma_f32_16x16x32_bf16(a_hi, b, c[nt], 0, 0, 0);
        }
      }
      int rws[4];
      #pragma unroll
      for (int i = 0; i < 4; i++) rws[i] = slots[sb + lg * 4 + i];
      float accv[4];
      if (iso < 0) {
        f32x2 w01 = {Wsh2[lr], Wsh2[16 + lr]};
        f32x2 w23 = {Wsh2[32 + lr], Wsh2[48 + lr]};
        #pragma unroll
        for (int i = 0; i < 4; i++) {
          const float* cb = contrib + iso_s[rws[i]] * 64;
          f32x2 v01 = (f32x2){c[0][i], c[1][i]} + (f32x2){cb[lr], cb[16 + lr]};
          f32x2 v23 = (f32x2){c[2][i], c[3][i]} + (f32x2){cb[32 + lr], cb[48 + lr]};
          f32x2 g01 = gelu2(v01), g23 = gelu2(v23);
          float a = g01.x * w01.x;
          a = __builtin_fmaf(g01.y, w01.y, a);
          a = __builtin_fmaf(g23.x, w23.x, a);
          a = __builtin_fmaf(g23.y, w23.y, a);
          accv[i] = a;
        }
      } else {
        f32x2 b01 = {biso1[iso * 64 + lr],      biso1[iso * 64 + 16 + lr]};
        f32x2 b23 = {biso1[iso * 64 + 32 + lr], biso1[iso * 64 + 48 + lr]};
        f32x2 x01 = {Wiso2[iso * 64 + lr],      Wiso2[iso * 64 + 16 + lr]};
        f32x2 x23 = {Wiso2[iso * 64 + 32 + lr], Wiso2[iso * 64 + 48 + lr]};
        #pragma unroll
        for (int i = 0; i < 4; i++) {
          f32x2 g01 = gelu2((f32x2){c[0][i], c[1][i]} + b01);
          f32x2 g23 = gelu2((f32x2){c[2][i], c[3][i]} + b23);
          float a = g01.x * x01.x;
          a = __builtin_fmaf(g01.y, x01.y, a);
          a = __builtin_fmaf(g23.x, x23.x, a);
          a = __builtin_fmaf(g23.y, x23.y, a);
          accv[i] = a;
        }
      }
      float tail = (iso < 0) ? bsh2v : biso2[iso];
      #pragma unroll
      for (int i = 0; i < 4; i++) {
        float a = accv[i];
        a += __shfl_xor(a, 1); a += __shfl_xor(a, 2);
        a += __shfl_xor(a, 4); a += __shfl_xor(a, 8);
        if (lr == 0) {
          int r = rws[i];
          if (iso < 0) sp[r] = a + tail;
          else if (r != 0xFF) eo[r] = a + tail;
        }
      }
    }
  }
  __syncthreads();                                    // B6

  // ---------------- epilogue: gated combine -------------------------------
  if (t < ROWS) {
    int r = t;
    float gate = gtab[iso_s[r]];
    out[r0 + r] = gate * eo[r] + (1.0f - gate) * sp[r];
  }
}

extern "C" void kernel_launch(void* const* d_in, const int* in_sizes, int n_in,
                              void* d_out, int out_size, void* d_ws, size_t ws_size,
                              hipStream_t stream) {
  const float* x         = (const float*)d_in[0];
  const int*   mol_idx   = (const int*)  d_in[1];
  const int*   iso_idx   = (const int*)  d_in[2];
  const float* mol_embed = (const float*)d_in[3];
  const float* iso_embed = (const float*)d_in[4];
  const float* W1  = (const float*)d_in[5];
  const float* b1  = (const float*)d_in[6];
  const float* g1  = (const float*)d_in[7];
  const float* be1 = (const float*)d_in[8];
  const float* W2  = (const float*)d_in[9];
  const float* b2  = (const float*)d_in[10];
  const float* g2  = (const float*)d_in[11];
  const float* be2 = (const float*)d_in[12];
  const float* Wsh1 = (const float*)d_in[13];
  const float* bsh1 = (const float*)d_in[14];
  const float* Wsh2 = (const float*)d_in[15];
  const float* bsh2 = (const float*)d_in[16];
  const float* Wiso1 = (const float*)d_in[17];
  const float* biso1 = (const float*)d_in[18];
  const float* Wiso2 = (const float*)d_in[19];
  const float* biso2 = (const float*)d_in[20];
  const float* Wg = (const float*)d_in[21];
  const float* bg = (const float*)d_in[22];
  float* out = (float*)d_out;
  unsigned short* wsf = (unsigned short*)d_ws;   // needs ~380 KB

  const int B = in_sizes[0] / 16;       // 262144
  const int grid = B / ROWS;            // 4096 blocks

  hipLaunchKernelGGL(prep_frags, dim3(96), dim3(256), 0, stream,
                     W1, W2, Wsh1, bsh1, Wiso1, iso_embed, Wg, bg, wsf);
  hipLaunchKernelGGL(corr_reg_fused, dim3(grid), dim3(THREADS), 0, stream,
                     x, mol_idx, iso_idx, mol_embed, iso_embed,
                     b1, g1, be1, b2, g2, be2,
                     bsh2, Wsh2, biso1, Wiso2, biso2, wsf, out);
}